// Round 2
// baseline (3807.892 us; speedup 1.0000x reference)
//
#include <hip/hip_runtime.h>
#include <cstdio>

typedef __bf16 bf16x8 __attribute__((ext_vector_type(8)));
typedef float f32x4 __attribute__((ext_vector_type(4)));
typedef int i32x4 __attribute__((ext_vector_type(4)));
typedef unsigned short u16x4 __attribute__((ext_vector_type(4)));

__device__ __forceinline__ float bf2f(unsigned short u) {
  union { unsigned int i; float f; } x; x.i = ((unsigned int)u) << 16; return x.f;
}
__device__ __forceinline__ unsigned short f2bf(float f) {
  union { float f; unsigned int i; } x; x.f = f;
  unsigned int r = x.i + 0x7fffu + ((x.i >> 16) & 1u);
  return (unsigned short)(r >> 16);
}

// ---------------- elementwise f32 -> bf16 cast (vec4) ----------------
__global__ __launch_bounds__(256) void k_cast(const float* __restrict__ in,
                                              unsigned short* __restrict__ out, int n4) {
  int i = blockIdx.x * 256 + threadIdx.x;
  if (i >= n4) return;
  f32x4 v = ((const f32x4*)in)[i];
  u16x4 o;
  o[0] = f2bf(v[0]); o[1] = f2bf(v[1]); o[2] = f2bf(v[2]); o[3] = f2bf(v[3]);
  ((u16x4*)out)[i] = o;
}

// -------- transpose-cast: src f32 [K][N] -> dst bf16 [N][K] --------
__global__ __launch_bounds__(256) void k_tcast(const float* __restrict__ src,
                                               unsigned short* __restrict__ dst,
                                               int K, int N) {
  __shared__ float tile[32][33];
  int gx = blockIdx.x * 32;  // N dim
  int gy = blockIdx.y * 32;  // K dim
  int t = threadIdx.x;
  int c = t & 31, r0 = t >> 5;
#pragma unroll
  for (int i = 0; i < 4; i++) {
    int r = r0 + i * 8;
    tile[r][c] = src[(size_t)(gy + r) * N + gx + c];
  }
  __syncthreads();
#pragma unroll
  for (int i = 0; i < 4; i++) {
    int r = r0 + i * 8;
    dst[(size_t)(gx + r) * K + gy + c] = f2bf(tile[c][r]);
  }
}

// ---------------- MFMA GEMM ----------------
// C[M][N] = A[M][K](bf16, row-major) * Wt[N][K]^T (bf16, N-major) + bias, optional exact GELU.
// 128x128 tile, BK=32, 256 threads = 4 waves (2x2), each wave 64x64 via 4x4 mfma 16x16x32.
template <bool GELU>
__global__ __launch_bounds__(256) void k_gemm(const unsigned short* __restrict__ A,
                                              const unsigned short* __restrict__ Bt,
                                              const float* __restrict__ bias,
                                              unsigned short* __restrict__ C,
                                              int M, int N, int K) {
  __shared__ unsigned short As[128 * 32];
  __shared__ unsigned short Bs[128 * 32];
  const int rowA0 = blockIdx.y * 128;
  const int colB0 = blockIdx.x * 128;
  const int t = threadIdx.x;
  const int w = t >> 6, lane = t & 63;
  const int wr = w >> 1, wc = w & 1;
  const int sr = t >> 2;           // staging row 0..63
  const int sc = (t & 3) * 8;      // staging k-offset (elems)

  f32x4 acc[4][4] = {};

  i32x4 va0, va1, vb0, vb1;
  const unsigned short* pa = A + (size_t)(rowA0 + sr) * K + sc;
  const unsigned short* pb = Bt + (size_t)(colB0 + sr) * K + sc;
  const size_t rstepA = (size_t)64 * K;

  va0 = *(const i32x4*)(pa);
  va1 = *(const i32x4*)(pa + rstepA);
  vb0 = *(const i32x4*)(pb);
  vb1 = *(const i32x4*)(pb + rstepA);

  const int ka = (lane >> 4) * 8;
  const int ra = lane & 15;

  for (int kk = 0; kk < K; kk += 32) {
    __syncthreads();
    *(i32x4*)&As[sr * 32 + sc] = va0;
    *(i32x4*)&As[(sr + 64) * 32 + sc] = va1;
    *(i32x4*)&Bs[sr * 32 + sc] = vb0;
    *(i32x4*)&Bs[(sr + 64) * 32 + sc] = vb1;
    __syncthreads();
    if (kk + 32 < K) {  // prefetch next K-step while computing this one
      va0 = *(const i32x4*)(pa + kk + 32);
      va1 = *(const i32x4*)(pa + rstepA + kk + 32);
      vb0 = *(const i32x4*)(pb + kk + 32);
      vb1 = *(const i32x4*)(pb + rstepA + kk + 32);
    }
    bf16x8 af[4], bfr[4];
#pragma unroll
    for (int m = 0; m < 4; m++)
      af[m] = *(const bf16x8*)&As[(wr * 64 + m * 16 + ra) * 32 + ka];
#pragma unroll
    for (int n = 0; n < 4; n++)
      bfr[n] = *(const bf16x8*)&Bs[(wc * 64 + n * 16 + ra) * 32 + ka];
#pragma unroll
    for (int m = 0; m < 4; m++)
#pragma unroll
      for (int n = 0; n < 4; n++)
        acc[m][n] = __builtin_amdgcn_mfma_f32_16x16x32_bf16(af[m], bfr[n], acc[m][n], 0, 0, 0);
  }

  // epilogue: D lane layout col = lane&15, row = (lane>>4)*4 + i
  const int cr = (lane >> 4) * 4;
  const int cc = lane & 15;
#pragma unroll
  for (int m = 0; m < 4; m++) {
    int grow = rowA0 + wr * 64 + m * 16 + cr;
#pragma unroll
    for (int n = 0; n < 4; n++) {
      int gcol = colB0 + wc * 64 + n * 16 + cc;
      float bv = bias[gcol];
#pragma unroll
      for (int i = 0; i < 4; i++) {
        float v = acc[m][n][i] + bv;
        if (GELU) v = 0.5f * v * (1.f + erff(v * 0.70710678118654752f));
        C[(size_t)(grow + i) * N + gcol] = f2bf(v);
      }
    }
  }
}

// ---------------- small GEMM (M=10): C[10][1024] = A[10][1024] * Wt[1024][1024]^T + bias ----------------
__global__ __launch_bounds__(256) void k_gemm10(const unsigned short* __restrict__ A,
                                                const unsigned short* __restrict__ Bt,
                                                const float* __restrict__ bias,
                                                unsigned short* __restrict__ C) {
  __shared__ float af[1024];
  int m = blockIdx.x, nb = blockIdx.y;
  int t = threadIdx.x;
#pragma unroll
  for (int i = 0; i < 4; i++) af[t * 4 + i] = bf2f(A[(size_t)m * 1024 + t * 4 + i]);
  __syncthreads();
  int w = t >> 6, lane = t & 63;
  for (int n = nb * 64 + w; n < nb * 64 + 64; n += 4) {
    const unsigned short* brow = Bt + (size_t)n * 1024 + lane * 16;
    float acc = 0.f;
#pragma unroll
    for (int j = 0; j < 16; j++) acc += af[lane * 16 + j] * bf2f(brow[j]);
#pragma unroll
    for (int o = 32; o; o >>= 1) acc += __shfl_xor(acc, o);
    if (lane == 0) C[(size_t)m * 1024 + n] = f2bf(acc + bias[n]);
  }
}

// ---------------- entmax-1.5 attention (one block per batch*head) ----------------
// Q rows (batch,l): col h*64+e.  K/V rows (batch,s) (or shared s).  Output written in
// torch Hopfield "mix" layout: out[batch][h*(L/16)+l/16][(l%16)*64+e].
template <int L, int S, bool SHARED>
__global__ __launch_bounds__(256) void k_attn(const unsigned short* __restrict__ Q,
                                              const unsigned short* __restrict__ Kb,
                                              const unsigned short* __restrict__ Vb,
                                              unsigned short* __restrict__ Out) {
  __shared__ float Qs[L * 64];
  __shared__ float Ks[S * 65];
  __shared__ float Vs[S * 64];
  int blk = blockIdx.x;
  int batch = blk >> 4, h = blk & 15;
  int t = threadIdx.x;
  for (int idx = t; idx < L * 64; idx += 256) {
    int l = idx >> 6, e = idx & 63;
    Qs[idx] = bf2f(Q[((size_t)(batch * L + l)) * 1024 + h * 64 + e]);
  }
  for (int idx = t; idx < S * 64; idx += 256) {
    int s = idx >> 6, e = idx & 63;
    size_t rb = SHARED ? (size_t)s : (size_t)(batch * S + s);
    Ks[s * 65 + e] = bf2f(Kb[rb * 1024 + h * 64 + e]);
    Vs[s * 64 + e] = bf2f(Vb[rb * 1024 + h * 64 + e]);
  }
  __syncthreads();
  int wv = t >> 6, lane = t & 63;
  const float hoff = (S == 64) ? 0.125f : (S == 32) ? 0.17677669529663687f : 0.31622776601683794f;
  for (int l = wv; l < L; l += 4) {
    float xs = -1e30f;
    if (lane < S) {
      float sc = 0.f;
#pragma unroll 16
      for (int e = 0; e < 64; e++) sc += Qs[l * 64 + e] * Ks[lane * 65 + e];
      xs = sc * 0.0625f;  // (1/sqrt(64)) * (alpha-1)=0.5
    }
    float mx = xs;
#pragma unroll
    for (int o = 32; o; o >>= 1) mx = fmaxf(mx, __shfl_xor(mx, o));
    float lo = mx - 1.f, hi = mx - hoff;
#pragma unroll 1
    for (int it = 0; it < 26; it++) {
      float mid = 0.5f * (lo + hi);
      float dd = fmaxf(xs - mid, 0.f);
      float f = dd * dd;
#pragma unroll
      for (int o = 32; o; o >>= 1) f += __shfl_xor(f, o);
      bool gt = f > 1.f;
      lo = gt ? mid : lo;
      hi = gt ? hi : mid;
    }
    float tau = 0.5f * (lo + hi);
    float dd = fmaxf(xs - tau, 0.f);
    float p = dd * dd;
    float ps = p;
#pragma unroll
    for (int o = 32; o; o >>= 1) ps += __shfl_xor(ps, o);
    p /= ps;
    float oacc = 0.f;
#pragma unroll
    for (int s = 0; s < S; s++) {
      float pp = __shfl(p, s);
      oacc += pp * Vs[s * 64 + lane];
    }
    int l_new = h * (L / 16) + (l >> 4);
    int c = (l & 15) * 64 + lane;
    Out[((size_t)(batch * L + l_new)) * 1024 + c] = f2bf(oacc);
  }
}

// ---------------- LayerNorm(a+b) * g + be, optional row permutation / f32 out ----------------
// MODE 0: orow=r. MODE 1: r=(b,t,s) dims(32,64) -> orow=(b,s,t). MODE 2: r=(b,s,t) dims(64,32) -> orow=(b,t,s).
template <int MODE, bool F32OUT>
__global__ __launch_bounds__(256) void k_ln(const unsigned short* __restrict__ a,
                                            const unsigned short* __restrict__ b,
                                            const float* __restrict__ g,
                                            const float* __restrict__ be,
                                            void* __restrict__ outp) {
  __shared__ float red[8];
  int r = blockIdx.x, t = threadIdx.x;
  size_t base = (size_t)r * 1024 + t * 4;
  u16x4 av = *(const u16x4*)(a + base);
  u16x4 bv = *(const u16x4*)(b + base);
  float x[4];
  float s = 0.f, ss = 0.f;
#pragma unroll
  for (int i = 0; i < 4; i++) {
    x[i] = bf2f(av[i]) + bf2f(bv[i]);
    s += x[i]; ss += x[i] * x[i];
  }
#pragma unroll
  for (int o = 32; o; o >>= 1) { s += __shfl_xor(s, o); ss += __shfl_xor(ss, o); }
  int w = t >> 6;
  if ((t & 63) == 0) { red[w] = s; red[4 + w] = ss; }
  __syncthreads();
  s = red[0] + red[1] + red[2] + red[3];
  ss = red[4] + red[5] + red[6] + red[7];
  float mean = s * (1.f / 1024.f);
  float var = ss * (1.f / 1024.f) - mean * mean;
  float rstd = rsqrtf(var + 1e-5f);
  int orow;
  if (MODE == 0) orow = r;
  else if (MODE == 1) { int bi = r >> 11, rem = r & 2047; int tt = rem >> 6, sd = rem & 63; orow = (bi << 11) + sd * 32 + tt; }
  else { int bi = r >> 11, rem = r & 2047; int sd = rem >> 5, tt = rem & 31; orow = (bi << 11) + tt * 64 + sd; }
  size_t ob = (size_t)orow * 1024 + t * 4;
  if (F32OUT) {
    f32x4 y;
#pragma unroll
    for (int i = 0; i < 4; i++) y[i] = (x[i] - mean) * rstd * g[t * 4 + i] + be[t * 4 + i];
    *(f32x4*)((float*)outp + ob) = y;
  } else {
    u16x4 y;
#pragma unroll
    for (int i = 0; i < 4; i++) y[i] = f2bf((x[i] - mean) * rstd * g[t * 4 + i] + be[t * 4 + i]);
    *(u16x4*)((unsigned short*)outp + ob) = y;
  }
}

// =======================================================================================

extern "C" void kernel_launch(void* const* d_in, const int* in_sizes, int n_in,
                              void* d_out, int out_size, void* d_ws, size_t ws_size,
                              hipStream_t stream) {
  // dims: b=8, ts_d=32, seg=64, d=1024, h=16, dff=4096, factor=10
  const int M = 16384;        // total rows (b*ts_d*seg)
  if (n_in < 43 || in_sizes[0] != 16777216 || in_sizes[25] != 10240 || in_sizes[34] != 4194304) {
    fprintf(stderr, "kernel_launch: unexpected input layout (n_in=%d s0=%d s25=%d s34=%d)\n",
            n_in, in_sizes[0], n_in > 25 ? in_sizes[25] : -1, n_in > 34 ? in_sizes[34] : -1);
    return;
  }
  const float* x = (const float*)d_in[0];
  const float* w[3][4]; const float* bia[3][4];
  for (int p = 0; p < 3; p++) {
    w[p][0] = (const float*)d_in[1 + 8 * p + 0]; bia[p][0] = (const float*)d_in[1 + 8 * p + 1]; // wq,bq
    w[p][1] = (const float*)d_in[1 + 8 * p + 2]; bia[p][1] = (const float*)d_in[1 + 8 * p + 3]; // wk,bk
    w[p][2] = (const float*)d_in[1 + 8 * p + 4]; bia[p][2] = (const float*)d_in[1 + 8 * p + 5]; // wv,bv
    w[p][3] = (const float*)d_in[1 + 8 * p + 6]; bia[p][3] = (const float*)d_in[1 + 8 * p + 7]; // wo,bo
  }
  const float* cs_key = (const float*)d_in[25];
  const float* ng[4]; const float* nb[4];
  for (int i = 0; i < 4; i++) { ng[i] = (const float*)d_in[26 + 2 * i]; nb[i] = (const float*)d_in[27 + 2 * i]; }
  const float* m_w1[2]; const float* m_b1[2]; const float* m_w2[2]; const float* m_b2[2];
  for (int i = 0; i < 2; i++) {
    m_w1[i] = (const float*)d_in[34 + 4 * i]; m_b1[i] = (const float*)d_in[35 + 4 * i];
    m_w2[i] = (const float*)d_in[36 + 4 * i]; m_b2[i] = (const float*)d_in[37 + 4 * i];
  }

  // ---- workspace bump allocator (budget: 256 MiB) ----
  char* base = (char*)d_ws; size_t off = 0;
  auto alloc = [&](size_t bytes) -> void* {
    off = (off + 255) & ~(size_t)255;
    void* p = base + off; off += bytes; return p;
  };
  unsigned short* Wt[3][4];
  for (int p = 0; p < 3; p++)
    for (int j = 0; j < 4; j++) Wt[p][j] = (unsigned short*)alloc((size_t)1024 * 1024 * 2);
  unsigned short* Wm1u = (unsigned short*)alloc((size_t)4096 * 1024 * 2); // m1_w1^T [4096][1024]
  unsigned short* Wm1d = (unsigned short*)alloc((size_t)1024 * 4096 * 2); // m1_w2^T [1024][4096]
  unsigned short* Wm2u = (unsigned short*)alloc((size_t)4096 * 1024 * 2);
  unsigned short* Wm2d = (unsigned short*)alloc((size_t)1024 * 4096 * 2);
  unsigned short* A[5];
  for (int i = 0; i < 5; i++) A[i] = (unsigned short*)alloc((size_t)M * 1024 * 2);
  const int MC = 4096;  // MLP M-chunk rows (keeps hidden buffer at 32 MiB)
  unsigned short* Hb = (unsigned short*)alloc((size_t)MC * 4096 * 2);
  unsigned short* KeyB = (unsigned short*)alloc((size_t)10 * 1024 * 2);
  unsigned short* Kcs = (unsigned short*)alloc((size_t)10 * 1024 * 2);
  unsigned short* Vcs = (unsigned short*)alloc((size_t)10 * 1024 * 2);
  if (off > ws_size) {
    fprintf(stderr, "kernel_launch: ws too small: need %zu have %zu\n", off, ws_size);
    return;
  }

  auto gemm = [&](const unsigned short* Ap, const unsigned short* Bt, const float* bi,
                  unsigned short* Cp, int Mm, int Nn, int Kk, bool gelu) {
    dim3 g(Nn / 128, Mm / 128);
    if (gelu) k_gemm<true><<<g, 256, 0, stream>>>(Ap, Bt, bi, Cp, Mm, Nn, Kk);
    else      k_gemm<false><<<g, 256, 0, stream>>>(Ap, Bt, bi, Cp, Mm, Nn, Kk);
  };
  // MLP over M-chunks: R = gelu(D@w1+b1)@w2 + b2, chunk rows to bound hidden buffer
  auto mlp = [&](const unsigned short* D, unsigned short* R,
                 const unsigned short* Wu, const float* b1,
                 const unsigned short* Wd, const float* b2) {
    for (int c = 0; c < M; c += MC) {
      gemm(D + (size_t)c * 1024, Wu, b1, Hb, MC, 4096, 1024, true);
      gemm(Hb, Wd, b2, R + (size_t)c * 1024, MC, 1024, 4096, false);
    }
  };

  // ---- weight prep ----
  for (int p = 0; p < 3; p++)
    for (int j = 0; j < 4; j++)
      k_tcast<<<dim3(32, 32), 256, 0, stream>>>(w[p][j], Wt[p][j], 1024, 1024);
  k_tcast<<<dim3(128, 32), 256, 0, stream>>>(m_w1[0], Wm1u, 1024, 4096);
  k_tcast<<<dim3(32, 128), 256, 0, stream>>>(m_w2[0], Wm1d, 4096, 1024);
  k_tcast<<<dim3(128, 32), 256, 0, stream>>>(m_w1[1], Wm2u, 1024, 4096);
  k_tcast<<<dim3(32, 128), 256, 0, stream>>>(m_w2[1], Wm2d, 4096, 1024);
  k_cast<<<16384, 256, 0, stream>>>(x, A[0], 16777216 / 4);
  k_cast<<<10, 256, 0, stream>>>(cs_key, KeyB, 10240 / 4);

  // ---- stage T (time attention over seg, B'=256, L=S=64) ----
  gemm(A[0], Wt[0][1], bia[0][1], A[1], M, 1024, 1024, false);             // Kt
  gemm(A[0], Wt[0][0], bia[0][0], A[2], M, 1024, 1024, false);             // Qt
  gemm(A[1], Wt[0][2], bia[0][2], A[3], M, 1024, 1024, false);             // Vt = Kt@wv+bv
  k_attn<64, 64, false><<<256 * 16, 256, 0, stream>>>(A[2], A[1], A[3], A[4]);
  gemm(A[4], Wt[0][3], bia[0][3], A[1], M, 1024, 1024, false);             // time_enc
  k_ln<0, false><<<M, 256, 0, stream>>>(A[0], A[1], ng[0], nb[0], A[2]);   // D = LN(x+enc)
  mlp(A[2], A[0], Wm1u, m_b1[0], Wm1d, m_b2[0]);                           // R = mlp(D)
  k_ln<1, false><<<M, 256, 0, stream>>>(A[2], A[0], ng[1], nb[1], A[3]);   // S = permute(LN(D+R))

  // ---- stage S (B'=512, L=32) ----
  k_gemm10<<<dim3(10, 16), 256, 0, stream>>>(KeyB, Wt[1][1], bia[1][1], Kcs);  // Kcs = key@wk+bk
  k_gemm10<<<dim3(10, 16), 256, 0, stream>>>(Kcs, Wt[1][2], bia[1][2], Vcs);   // Vcs = Kcs@wv+bv
  gemm(A[3], Wt[1][0], bia[1][0], A[0], M, 1024, 1024, false);             // Qcs
  k_attn<32, 10, true><<<512 * 16, 256, 0, stream>>>(A[0], Kcs, Vcs, A[1]);
  gemm(A[1], Wt[1][3], bia[1][3], A[2], M, 1024, 1024, false);             // SH
  gemm(A[3], Wt[2][1], bia[2][1], A[0], M, 1024, 1024, false);             // Khp
  gemm(A[3], Wt[2][0], bia[2][0], A[1], M, 1024, 1024, false);             // Qhp
  gemm(A[0], Wt[2][2], bia[2][2], A[4], M, 1024, 1024, false);             // Vhp
  k_attn<32, 32, false><<<512 * 16, 256, 0, stream>>>(A[1], A[0], A[4], A[3]);
  gemm(A[3], Wt[2][3], bia[2][3], A[0], M, 1024, 1024, false);             // PH
  k_ln<0, false><<<M, 256, 0, stream>>>(A[2], A[0], ng[2], nb[2], A[1]);   // DE = LN(SH+PH)
  mlp(A[1], A[0], Wm2u, m_b1[1], Wm2d, m_b2[1]);
  k_ln<2, true><<<M, 256, 0, stream>>>(A[1], A[0], ng[3], nb[3], d_out);   // final LN + permute, f32
}

// Round 3
// 1772.404 us; speedup vs baseline: 2.1484x; 2.1484x over previous
//
#include <hip/hip_runtime.h>
#include <cstdio>

typedef __bf16 bf16x8 __attribute__((ext_vector_type(8)));
typedef float f32x4 __attribute__((ext_vector_type(4)));
typedef int i32x4 __attribute__((ext_vector_type(4)));
typedef unsigned short u16x4 __attribute__((ext_vector_type(4)));

__device__ __forceinline__ float bf2f(unsigned short u) {
  union { unsigned int i; float f; } x; x.i = ((unsigned int)u) << 16; return x.f;
}
__device__ __forceinline__ unsigned short f2bf(float f) {
  union { float f; unsigned int i; } x; x.f = f;
  unsigned int r = x.i + 0x7fffu + ((x.i >> 16) & 1u);
  return (unsigned short)(r >> 16);
}

// async global->LDS, 16B per lane; LDS dest is wave-uniform base + lane*16
__device__ __forceinline__ void gl2lds16(const unsigned short* g, unsigned short* l) {
  __builtin_amdgcn_global_load_lds((const __attribute__((address_space(1))) unsigned int*)g,
                                   (__attribute__((address_space(3))) unsigned int*)l, 16, 0, 0);
}

// ---------------- elementwise f32 -> bf16 cast (vec4) ----------------
__global__ __launch_bounds__(256) void k_cast(const float* __restrict__ in,
                                              unsigned short* __restrict__ out, int n4) {
  int i = blockIdx.x * 256 + threadIdx.x;
  if (i >= n4) return;
  f32x4 v = ((const f32x4*)in)[i];
  u16x4 o;
  o[0] = f2bf(v[0]); o[1] = f2bf(v[1]); o[2] = f2bf(v[2]); o[3] = f2bf(v[3]);
  ((u16x4*)out)[i] = o;
}

// -------- transpose-cast: src f32 [K][N] -> dst bf16 [N][K] --------
__global__ __launch_bounds__(256) void k_tcast(const float* __restrict__ src,
                                               unsigned short* __restrict__ dst,
                                               int K, int N) {
  __shared__ float tile[32][33];
  int gx = blockIdx.x * 32;  // N dim
  int gy = blockIdx.y * 32;  // K dim
  int t = threadIdx.x;
  int c = t & 31, r0 = t >> 5;
#pragma unroll
  for (int i = 0; i < 4; i++) {
    int r = r0 + i * 8;
    tile[r][c] = src[(size_t)(gy + r) * N + gx + c];
  }
  __syncthreads();
#pragma unroll
  for (int i = 0; i < 4; i++) {
    int r = r0 + i * 8;
    dst[(size_t)(gx + r) * K + gy + c] = f2bf(tile[c][r]);
  }
}

// ---------------- MFMA GEMM (m97 structure: global_load_lds + dbuf) ----------------
// C[M][N] = A[M][K](bf16 row-major) * Wt[N][K]^T + bias, optional exact GELU.
// 128x128 tile, BK=32, 256 threads = 4 waves (2x2), each wave 64x64 via 4x4 mfma 16x16x32.
template <bool GELU>
__global__ __launch_bounds__(256) void k_gemm(const unsigned short* __restrict__ A,
                                              const unsigned short* __restrict__ Bt,
                                              const float* __restrict__ bias,
                                              unsigned short* __restrict__ C,
                                              int M, int N, int K) {
  __shared__ unsigned short As[2][128 * 32];
  __shared__ unsigned short Bs[2][128 * 32];
  const int rowA0 = blockIdx.y * 128, colB0 = blockIdx.x * 128;
  const int t = threadIdx.x, w = t >> 6, lane = t & 63;
  const int wr = w >> 1, wc = w & 1;
  // staging coords: wave w covers rows w*16..w*16+15 (lane>>2), chunk (lane&3)*8 elems
  const int srow = w * 16 + (lane >> 2);
  const unsigned short* pa = A + (size_t)(rowA0 + srow) * K + (lane & 3) * 8;
  const unsigned short* pb = Bt + (size_t)(colB0 + srow) * K + (lane & 3) * 8;
  const size_t row64 = (size_t)64 * K;

  f32x4 acc[4][4] = {};
  const int ka = (lane >> 4) * 8, ra = lane & 15;

  auto stage = [&](int buf, int kk) {
    gl2lds16(pa + kk,         &As[buf][w * 512]);
    gl2lds16(pa + row64 + kk, &As[buf][2048 + w * 512]);
    gl2lds16(pb + kk,         &Bs[buf][w * 512]);
    gl2lds16(pb + row64 + kk, &Bs[buf][2048 + w * 512]);
  };
  stage(0, 0);
  int buf = 0;
  for (int kk = 0; kk < K; kk += 32) {
    asm volatile("s_waitcnt vmcnt(0)" ::: "memory");
    __syncthreads();
    if (kk + 32 < K) stage(buf ^ 1, kk + 32);  // prefetch next K-step into other buffer
    bf16x8 af[4], bfr[4];
#pragma unroll
    for (int m = 0; m < 4; m++)
      af[m] = *(const bf16x8*)&As[buf][(wr * 64 + m * 16 + ra) * 32 + ka];
#pragma unroll
    for (int n = 0; n < 4; n++)
      bfr[n] = *(const bf16x8*)&Bs[buf][(wc * 64 + n * 16 + ra) * 32 + ka];
#pragma unroll
    for (int m = 0; m < 4; m++)
#pragma unroll
      for (int n = 0; n < 4; n++)
        acc[m][n] = __builtin_amdgcn_mfma_f32_16x16x32_bf16(af[m], bfr[n], acc[m][n], 0, 0, 0);
    buf ^= 1;
  }

  // epilogue: D lane layout col = lane&15, row = (lane>>4)*4 + i
  const int cr = (lane >> 4) * 4;
  const int cc = lane & 15;
#pragma unroll
  for (int m = 0; m < 4; m++) {
    int grow = rowA0 + wr * 64 + m * 16 + cr;
#pragma unroll
    for (int n = 0; n < 4; n++) {
      int gcol = colB0 + wc * 64 + n * 16 + cc;
      float bv = bias[gcol];
#pragma unroll
      for (int i = 0; i < 4; i++) {
        float v = acc[m][n][i] + bv;
        if (GELU) v = 0.5f * v * (1.f + erff(v * 0.70710678118654752f));
        C[(size_t)(grow + i) * N + gcol] = f2bf(v);
      }
    }
  }
}

// ---------------- small GEMM (M=10): C[10][1024] = A[10][1024] * Wt^T + bias ----------------
__global__ __launch_bounds__(256) void k_gemm10(const unsigned short* __restrict__ A,
                                                const unsigned short* __restrict__ Bt,
                                                const float* __restrict__ bias,
                                                unsigned short* __restrict__ C) {
  __shared__ float af[1024];
  int m = blockIdx.x, nb = blockIdx.y;
  int t = threadIdx.x;
#pragma unroll
  for (int i = 0; i < 4; i++) af[t * 4 + i] = bf2f(A[(size_t)m * 1024 + t * 4 + i]);
  __syncthreads();
  int w = t >> 6, lane = t & 63;
  for (int n = nb * 64 + w; n < nb * 64 + 64; n += 4) {
    const unsigned short* brow = Bt + (size_t)n * 1024 + lane * 16;
    float acc = 0.f;
#pragma unroll
    for (int j = 0; j < 16; j++) acc += af[lane * 16 + j] * bf2f(brow[j]);
#pragma unroll
    for (int o = 32; o; o >>= 1) acc += __shfl_xor(acc, o);
    if (lane == 0) C[(size_t)m * 1024 + n] = f2bf(acc + bias[n]);
  }
}

// ---------------- entmax-1.5 attention, MFMA version ----------------
// One block per (batch,head). QK^T via MFMA -> scores LDS (f32) -> register bisection
// (G lanes per row, group shfl_xor reduce) -> P bf16 in LDS -> PV via MFMA.
// Output in torch Hopfield "mix" layout: out[batch][h*(L/16)+l/16][(l%16)*64+e].
template <int L, int S, bool SHARED>
__global__ __launch_bounds__(256) void k_attn(const unsigned short* __restrict__ Q,
                                              const unsigned short* __restrict__ Kb,
                                              const unsigned short* __restrict__ Vb,
                                              unsigned short* __restrict__ Out) {
  constexpr int SP = (S <= 32) ? 32 : 64;  // S padded to MFMA K-multiple
  constexpr int QST = 72;                  // Q/K row stride (bf16), pad for bank spread
  constexpr int VST = SP + 8;              // Vt/P row stride
  constexpr int CST = SP + 4;              // scores row stride (f32)
  __shared__ unsigned short Qs[L * QST];   // reused as P (stride VST) in phase 3
  __shared__ unsigned short Ks[SP * QST];
  __shared__ unsigned short Vt[64 * VST];  // Vt[e][s] = V[s][e]
  __shared__ float Sc[L * CST];
  __shared__ float Rps[L];
  const int blk = blockIdx.x, batch = blk >> 4, h = blk & 15;
  const int t = threadIdx.x, w = t >> 6, lane = t & 63;

  // --- stage Q (16B chunks) ---
  for (int c = t; c < L * 8; c += 256) {
    int r = c >> 3, ch = (c & 7) * 8;
    *(i32x4*)&Qs[r * QST + ch] =
        *(const i32x4*)&Q[((size_t)(batch * L + r)) * 1024 + h * 64 + ch];
  }
  // --- stage K rows (zero rows >= S) ---
  for (int c = t; c < SP * 8; c += 256) {
    int r = c >> 3, ch = (c & 7) * 8;
    i32x4 v = {0, 0, 0, 0};
    if (r < S) {
      size_t rb = SHARED ? (size_t)r : (size_t)(batch * S + r);
      v = *(const i32x4*)&Kb[rb * 1024 + h * 64 + ch];
    }
    *(i32x4*)&Ks[r * QST + ch] = v;
  }
  // --- stage V transposed (zero cols >= S) ---
  for (int c = t; c < SP * 64; c += 256) {
    int s = c >> 6, e = c & 63;
    unsigned short v = 0;
    if (s < S) {
      size_t rb = SHARED ? (size_t)s : (size_t)(batch * S + s);
      v = Vb[rb * 1024 + h * 64 + e];
    }
    Vt[e * VST + s] = v;
  }
  __syncthreads();

  const int ka = (lane >> 4) * 8, ra = lane & 15;
  const int cr = (lane >> 4) * 4, cc = lane & 15;
  // --- phase 1: scores = (Q K^T) * 0.5/sqrt(64) ---
  constexpr int NT = SP / 16, TT = (L / 16) * NT;
  for (int tt = w; tt < TT; tt += 4) {
    int m = tt / NT, n = tt % NT;
    f32x4 a = {0.f, 0.f, 0.f, 0.f};
#pragma unroll
    for (int ks = 0; ks < 2; ks++) {  // E=64 -> 2 K-steps
      bf16x8 af = *(const bf16x8*)&Qs[(m * 16 + ra) * QST + ks * 32 + ka];
      bf16x8 bf = *(const bf16x8*)&Ks[(n * 16 + ra) * QST + ks * 32 + ka];
      a = __builtin_amdgcn_mfma_f32_16x16x32_bf16(af, bf, a, 0, 0, 0);
    }
#pragma unroll
    for (int i = 0; i < 4; i++)
      Sc[(m * 16 + cr + i) * CST + n * 16 + cc] = a[i] * 0.0625f;
  }
  __syncthreads();

  // --- phase 2: bisection, G lanes per row, scores in registers ---
  constexpr int G = 256 / L, RW = 64 / G, SL = SP / G;
  const int row = w * RW + lane / G, sub = lane % G;
  float xs[SL];
#pragma unroll
  for (int j = 0; j < SL; j++) {
    int s = sub * SL + j;
    float v = Sc[row * CST + s];
    if (S < SP && s >= S) v = -1e30f;
    xs[j] = v;
  }
  float mx = xs[0];
#pragma unroll
  for (int j = 1; j < SL; j++) mx = fmaxf(mx, xs[j]);
#pragma unroll
  for (int o = G / 2; o; o >>= 1) mx = fmaxf(mx, __shfl_xor(mx, o));
  const float hoff = (S == 64) ? 0.125f : (S == 32) ? 0.17677669529663687f : 0.31622776601683794f;
  float lo = mx - 1.f, hi = mx - hoff;
#pragma unroll 1
  for (int it = 0; it < 26; it++) {
    float mid = 0.5f * (lo + hi);
    float f = 0.f;
#pragma unroll
    for (int j = 0; j < SL; j++) { float dd = fmaxf(xs[j] - mid, 0.f); f += dd * dd; }
#pragma unroll
    for (int o = G / 2; o; o >>= 1) f += __shfl_xor(f, o);
    bool gt = f > 1.f;
    lo = gt ? mid : lo;
    hi = gt ? hi : mid;
  }
  float tau = 0.5f * (lo + hi);
  float ps = 0.f;
#pragma unroll
  for (int j = 0; j < SL; j++) { float dd = fmaxf(xs[j] - tau, 0.f); xs[j] = dd * dd; ps += xs[j]; }
#pragma unroll
  for (int o = G / 2; o; o >>= 1) ps += __shfl_xor(ps, o);
  if (sub == 0) Rps[row] = 1.f / ps;
  unsigned short* Pb = Qs;  // reuse Qs as P (unnormalized, bf16, stride VST)
#pragma unroll
  for (int j = 0; j < SL; j += 4) {
    u16x4 pv;
#pragma unroll
    for (int jj = 0; jj < 4; jj++) pv[jj] = f2bf(xs[j + jj]);
    *(u16x4*)&Pb[row * VST + sub * SL + j] = pv;
  }
  __syncthreads();

  // --- phase 3: out = (P . Vt^T) * Rps[row] ---
  constexpr int TT2 = (L / 16) * 4;
  for (int tt = w; tt < TT2; tt += 4) {
    int m = tt >> 2, n = tt & 3;
    f32x4 a = {0.f, 0.f, 0.f, 0.f};
#pragma unroll
    for (int ks = 0; ks < SP / 32; ks++) {
      bf16x8 af = *(const bf16x8*)&Pb[(m * 16 + ra) * VST + ks * 32 + ka];
      bf16x8 bf = *(const bf16x8*)&Vt[(n * 16 + ra) * VST + ks * 32 + ka];
      a = __builtin_amdgcn_mfma_f32_16x16x32_bf16(af, bf, a, 0, 0, 0);
    }
#pragma unroll
    for (int i = 0; i < 4; i++) {
      int l = m * 16 + cr + i, e = n * 16 + cc;
      float val = a[i] * Rps[l];
      int l_new = h * (L / 16) + (l >> 4);
      int cg = (l & 15) * 64 + e;
      Out[((size_t)(batch * L + l_new)) * 1024 + cg] = f2bf(val);
    }
  }
}

// ---------------- LayerNorm(a+b) * g + be, optional row permutation / f32 out ----------------
// MODE 0: orow=r. MODE 1: r=(b,t,s) dims(32,64) -> orow=(b,s,t). MODE 2: r=(b,s,t) dims(64,32) -> orow=(b,t,s).
template <int MODE, bool F32OUT>
__global__ __launch_bounds__(256) void k_ln(const unsigned short* __restrict__ a,
                                            const unsigned short* __restrict__ b,
                                            const float* __restrict__ g,
                                            const float* __restrict__ be,
                                            void* __restrict__ outp) {
  __shared__ float red[8];
  int r = blockIdx.x, t = threadIdx.x;
  size_t base = (size_t)r * 1024 + t * 4;
  u16x4 av = *(const u16x4*)(a + base);
  u16x4 bv = *(const u16x4*)(b + base);
  float x[4];
  float s = 0.f, ss = 0.f;
#pragma unroll
  for (int i = 0; i < 4; i++) {
    x[i] = bf2f(av[i]) + bf2f(bv[i]);
    s += x[i]; ss += x[i] * x[i];
  }
#pragma unroll
  for (int o = 32; o; o >>= 1) { s += __shfl_xor(s, o); ss += __shfl_xor(ss, o); }
  int w = t >> 6;
  if ((t & 63) == 0) { red[w] = s; red[4 + w] = ss; }
  __syncthreads();
  s = red[0] + red[1] + red[2] + red[3];
  ss = red[4] + red[5] + red[6] + red[7];
  float mean = s * (1.f / 1024.f);
  float var = ss * (1.f / 1024.f) - mean * mean;
  float rstd = rsqrtf(var + 1e-5f);
  int orow;
  if (MODE == 0) orow = r;
  else if (MODE == 1) { int bi = r >> 11, rem = r & 2047; int tt = rem >> 6, sd = rem & 63; orow = (bi << 11) + sd * 32 + tt; }
  else { int bi = r >> 11, rem = r & 2047; int sd = rem >> 5, tt = rem & 31; orow = (bi << 11) + tt * 64 + sd; }
  size_t ob = (size_t)orow * 1024 + t * 4;
  if (F32OUT) {
    f32x4 y;
#pragma unroll
    for (int i = 0; i < 4; i++) y[i] = (x[i] - mean) * rstd * g[t * 4 + i] + be[t * 4 + i];
    *(f32x4*)((float*)outp + ob) = y;
  } else {
    u16x4 y;
#pragma unroll
    for (int i = 0; i < 4; i++) y[i] = f2bf((x[i] - mean) * rstd * g[t * 4 + i] + be[t * 4 + i]);
    *(u16x4*)((unsigned short*)outp + ob) = y;
  }
}

// =======================================================================================

extern "C" void kernel_launch(void* const* d_in, const int* in_sizes, int n_in,
                              void* d_out, int out_size, void* d_ws, size_t ws_size,
                              hipStream_t stream) {
  // dims: b=8, ts_d=32, seg=64, d=1024, h=16, dff=4096, factor=10
  const int M = 16384;
  if (n_in < 43 || in_sizes[0] != 16777216 || in_sizes[25] != 10240 || in_sizes[34] != 4194304) {
    fprintf(stderr, "kernel_launch: unexpected input layout (n_in=%d s0=%d s25=%d s34=%d)\n",
            n_in, in_sizes[0], n_in > 25 ? in_sizes[25] : -1, n_in > 34 ? in_sizes[34] : -1);
    return;
  }
  const float* x = (const float*)d_in[0];
  const float* w[3][4]; const float* bia[3][4];
  for (int p = 0; p < 3; p++) {
    w[p][0] = (const float*)d_in[1 + 8 * p + 0]; bia[p][0] = (const float*)d_in[1 + 8 * p + 1];
    w[p][1] = (const float*)d_in[1 + 8 * p + 2]; bia[p][1] = (const float*)d_in[1 + 8 * p + 3];
    w[p][2] = (const float*)d_in[1 + 8 * p + 4]; bia[p][2] = (const float*)d_in[1 + 8 * p + 5];
    w[p][3] = (const float*)d_in[1 + 8 * p + 6]; bia[p][3] = (const float*)d_in[1 + 8 * p + 7];
  }
  const float* cs_key = (const float*)d_in[25];
  const float* ng[4]; const float* nb[4];
  for (int i = 0; i < 4; i++) { ng[i] = (const float*)d_in[26 + 2 * i]; nb[i] = (const float*)d_in[27 + 2 * i]; }
  const float* m_w1[2]; const float* m_b1[2]; const float* m_w2[2]; const float* m_b2[2];
  for (int i = 0; i < 2; i++) {
    m_w1[i] = (const float*)d_in[34 + 4 * i]; m_b1[i] = (const float*)d_in[35 + 4 * i];
    m_w2[i] = (const float*)d_in[36 + 4 * i]; m_b2[i] = (const float*)d_in[37 + 4 * i];
  }

  // ---- workspace bump allocator (budget 256 MiB; total used ~216 MiB) ----
  char* base = (char*)d_ws; size_t off = 0;
  auto alloc = [&](size_t bytes) -> void* {
    off = (off + 255) & ~(size_t)255;
    void* p = base + off; off += bytes; return p;
  };
  unsigned short* Wt[3][4];
  for (int p = 0; p < 3; p++)
    for (int j = 0; j < 4; j++) Wt[p][j] = (unsigned short*)alloc((size_t)1024 * 1024 * 2);
  unsigned short* Wm1u = (unsigned short*)alloc((size_t)4096 * 1024 * 2);
  unsigned short* Wm1d = (unsigned short*)alloc((size_t)1024 * 4096 * 2);
  unsigned short* Wm2u = (unsigned short*)alloc((size_t)4096 * 1024 * 2);
  unsigned short* Wm2d = (unsigned short*)alloc((size_t)1024 * 4096 * 2);
  // A[0..4]: 32 MiB each, CONTIGUOUS (bump keeps 32MiB blocks adjacent; 256-aligned sizes)
  unsigned short* A[5];
  for (int i = 0; i < 5; i++) A[i] = (unsigned short*)alloc((size_t)M * 1024 * 2);
  unsigned short* KeyB = (unsigned short*)alloc((size_t)10 * 1024 * 2);
  unsigned short* Kcs = (unsigned short*)alloc((size_t)10 * 1024 * 2);
  unsigned short* Vcs = (unsigned short*)alloc((size_t)10 * 1024 * 2);
  if (off > ws_size) {
    fprintf(stderr, "kernel_launch: ws too small: need %zu have %zu\n", off, ws_size);
    return;
  }
  const int MC = 8192;                 // MLP M-chunk rows
  unsigned short* HbT = A[0];          // 64 MiB scratch = A0+A1 region (dead during stage-T MLP)
  unsigned short* HbS = A[1];          // 64 MiB scratch = A1+A2 region (dead during stage-S MLP)

  auto gemm = [&](const unsigned short* Ap, const unsigned short* Bt, const float* bi,
                  unsigned short* Cp, int Mm, int Nn, int Kk, bool gelu) {
    dim3 g(Nn / 128, Mm / 128);
    if (gelu) k_gemm<true><<<g, 256, 0, stream>>>(Ap, Bt, bi, Cp, Mm, Nn, Kk);
    else      k_gemm<false><<<g, 256, 0, stream>>>(Ap, Bt, bi, Cp, Mm, Nn, Kk);
  };

  // ---- weight prep ----
  for (int p = 0; p < 3; p++)
    for (int j = 0; j < 4; j++)
      k_tcast<<<dim3(32, 32), 256, 0, stream>>>(w[p][j], Wt[p][j], 1024, 1024);
  k_tcast<<<dim3(128, 32), 256, 0, stream>>>(m_w1[0], Wm1u, 1024, 4096);
  k_tcast<<<dim3(32, 128), 256, 0, stream>>>(m_w2[0], Wm1d, 4096, 1024);
  k_tcast<<<dim3(128, 32), 256, 0, stream>>>(m_w1[1], Wm2u, 1024, 4096);
  k_tcast<<<dim3(32, 128), 256, 0, stream>>>(m_w2[1], Wm2d, 4096, 1024);
  k_cast<<<16384, 256, 0, stream>>>(x, A[0], 16777216 / 4);
  k_cast<<<10, 256, 0, stream>>>(cs_key, KeyB, 10240 / 4);

  // ---- stage T (time attention over seg; 256 batches, L=S=64) ----
  gemm(A[0], Wt[0][1], bia[0][1], A[1], M, 1024, 1024, false);             // K
  gemm(A[0], Wt[0][0], bia[0][0], A[2], M, 1024, 1024, false);             // Q
  gemm(A[1], Wt[0][2], bia[0][2], A[3], M, 1024, 1024, false);             // V = K@wv+bv
  k_attn<64, 64, false><<<256 * 16, 256, 0, stream>>>(A[2], A[1], A[3], A[4]);
  gemm(A[4], Wt[0][3], bia[0][3], A[1], M, 1024, 1024, false);             // time_enc
  k_ln<0, false><<<M, 256, 0, stream>>>(A[0], A[1], ng[0], nb[0], A[2]);   // D = LN(x+enc)
  for (int c = 0; c < M; c += MC) {                                        // R = mlp(D) -> A4
    gemm(A[2] + (size_t)c * 1024, Wm1u, m_b1[0], HbT, MC, 4096, 1024, true);
    gemm(HbT, Wm1d, m_b2[0], A[4] + (size_t)c * 1024, MC, 1024, 4096, false);
  }
  k_ln<1, false><<<M, 256, 0, stream>>>(A[2], A[4], ng[1], nb[1], A[3]);   // S = permute(LN(D+R))

  // ---- stage S (512 batches, L=32) ----
  k_gemm10<<<dim3(10, 16), 256, 0, stream>>>(KeyB, Wt[1][1], bia[1][1], Kcs);
  k_gemm10<<<dim3(10, 16), 256, 0, stream>>>(Kcs, Wt[1][2], bia[1][2], Vcs);
  gemm(A[3], Wt[1][0], bia[1][0], A[0], M, 1024, 1024, false);             // Qcs
  k_attn<32, 10, true><<<512 * 16, 256, 0, stream>>>(A[0], Kcs, Vcs, A[1]);
  gemm(A[1], Wt[1][3], bia[1][3], A[2], M, 1024, 1024, false);             // SH
  gemm(A[3], Wt[2][1], bia[2][1], A[0], M, 1024, 1024, false);             // Khp
  gemm(A[3], Wt[2][0], bia[2][0], A[1], M, 1024, 1024, false);             // Qhp
  gemm(A[0], Wt[2][2], bia[2][2], A[4], M, 1024, 1024, false);             // Vhp
  k_attn<32, 32, false><<<512 * 16, 256, 0, stream>>>(A[1], A[0], A[4], A[3]);
  gemm(A[3], Wt[2][3], bia[2][3], A[1], M, 1024, 1024, false);             // PH
  k_ln<0, false><<<M, 256, 0, stream>>>(A[2], A[1], ng[2], nb[2], A[0]);   // DE = LN(SH+PH)
  for (int c = 0; c < M; c += MC) {                                        // mlp2 -> A3
    gemm(A[0] + (size_t)c * 1024, Wm2u, m_b1[1], HbS, MC, 4096, 1024, true);
    gemm(HbS, Wm2d, m_b2[1], A[3] + (size_t)c * 1024, MC, 1024, 4096, false);
  }
  k_ln<2, true><<<M, 256, 0, stream>>>(A[0], A[3], ng[3], nb[3], d_out);   // final LN+permute, f32
}

// Round 4
// 1653.564 us; speedup vs baseline: 2.3028x; 1.0719x over previous
//
#include <hip/hip_runtime.h>
#include <cstdio>

typedef __bf16 bf16x8 __attribute__((ext_vector_type(8)));
typedef float f32x4 __attribute__((ext_vector_type(4)));
typedef int i32x4 __attribute__((ext_vector_type(4)));
typedef unsigned short u16x4 __attribute__((ext_vector_type(4)));

__device__ __forceinline__ float bf2f(unsigned short u) {
  union { unsigned int i; float f; } x; x.i = ((unsigned int)u) << 16; return x.f;
}
__device__ __forceinline__ unsigned short f2bf(float f) {
  union { float f; unsigned int i; } x; x.f = f;
  unsigned int r = x.i + 0x7fffu + ((x.i >> 16) & 1u);
  return (unsigned short)(r >> 16);
}

// async global->LDS, 16B per lane; LDS dest is wave-uniform base + lane*16
__device__ __forceinline__ void gl2lds16(const unsigned short* g, unsigned short* l) {
  __builtin_amdgcn_global_load_lds((const __attribute__((address_space(1))) unsigned int*)g,
                                   (__attribute__((address_space(3))) unsigned int*)l, 16, 0, 0);
}

// ---------------- elementwise f32 -> bf16 cast (vec4) ----------------
__global__ __launch_bounds__(256) void k_cast(const float* __restrict__ in,
                                              unsigned short* __restrict__ out, int n4) {
  int i = blockIdx.x * 256 + threadIdx.x;
  if (i >= n4) return;
  f32x4 v = ((const f32x4*)in)[i];
  u16x4 o;
  o[0] = f2bf(v[0]); o[1] = f2bf(v[1]); o[2] = f2bf(v[2]); o[3] = f2bf(v[3]);
  ((u16x4*)out)[i] = o;
}

// -------- transpose-cast: src f32 [K][N] -> dst bf16 [N][K] --------
__global__ __launch_bounds__(256) void k_tcast(const float* __restrict__ src,
                                               unsigned short* __restrict__ dst,
                                               int K, int N) {
  __shared__ float tile[32][33];
  int gx = blockIdx.x * 32;  // N dim
  int gy = blockIdx.y * 32;  // K dim
  int t = threadIdx.x;
  int c = t & 31, r0 = t >> 5;
#pragma unroll
  for (int i = 0; i < 4; i++) {
    int r = r0 + i * 8;
    tile[r][c] = src[(size_t)(gy + r) * N + gx + c];
  }
  __syncthreads();
#pragma unroll
  for (int i = 0; i < 4; i++) {
    int r = r0 + i * 8;
    dst[(size_t)(gx + r) * K + gy + c] = f2bf(tile[c][r]);
  }
}

// ---------------- MFMA GEMM (m97 structure + T2 source-swizzle + T1 XCD swizzle) ----------------
// C[M][N] = A[M][K](bf16 row-major) * Wt[N][K]^T + bias, optional exact GELU.
// 128x128 tile, BK=32, 256 threads = 4 waves (2x2), each wave 64x64 via 4x4 mfma 16x16x32.
// LDS tile [128][32] linear (global_load_lds requirement); bank-conflict fix via
// pre-swizzled GLOBAL chunk c = g ^ ((row>>1)&3) and matching XOR on the ds_read address.
template <bool GELU>
__global__ __launch_bounds__(256) void k_gemm(const unsigned short* __restrict__ A,
                                              const unsigned short* __restrict__ Bt,
                                              const float* __restrict__ bias,
                                              unsigned short* __restrict__ C,
                                              int M, int N, int K) {
  __shared__ unsigned short As[2][128 * 32];
  __shared__ unsigned short Bs[2][128 * 32];
  // T1: XCD-aware block swizzle (bijective; all grids here are multiples of 8)
  int nwg = gridDim.x * gridDim.y;
  int lin = blockIdx.y * gridDim.x + blockIdx.x;
  int swz = (nwg & 7) ? lin : ((lin & 7) * (nwg >> 3) + (lin >> 3));
  const int rowA0 = (swz / gridDim.x) * 128, colB0 = (swz % gridDim.x) * 128;
  const int t = threadIdx.x, w = t >> 6, lane = t & 63;
  const int wr = w >> 1, wc = w & 1;
  // staging: wave w covers rows w*16..w*16+15 (lane>>2); global chunk pre-swizzled
  const int srow = w * 16 + (lane >> 2);
  const int schunk = (lane & 3) ^ ((lane >> 3) & 3);  // = g ^ ((row>>1)&3)
  const unsigned short* pa = A + (size_t)(rowA0 + srow) * K + schunk * 8;
  const unsigned short* pb = Bt + (size_t)(colB0 + srow) * K + schunk * 8;
  const size_t row64 = (size_t)64 * K;

  f32x4 acc[4][4] = {};
  const int ra = lane & 15;
  // fragment read: logical granule g = lane>>4, physical gp = g ^ ((ra>>1)&3)
  const int gp8 = (((lane >> 4) ^ ((ra >> 1) & 3)) * 8);

  auto stage = [&](int buf, int kk) {
    gl2lds16(pa + kk,         &As[buf][w * 512]);
    gl2lds16(pa + row64 + kk, &As[buf][2048 + w * 512]);
    gl2lds16(pb + kk,         &Bs[buf][w * 512]);
    gl2lds16(pb + row64 + kk, &Bs[buf][2048 + w * 512]);
  };
  stage(0, 0);
  int buf = 0;
  for (int kk = 0; kk < K; kk += 32) {
    asm volatile("s_waitcnt vmcnt(0)" ::: "memory");
    __syncthreads();
    if (kk + 32 < K) stage(buf ^ 1, kk + 32);  // prefetch next K-step into other buffer
    bf16x8 af[4], bfr[4];
#pragma unroll
    for (int m = 0; m < 4; m++)
      af[m] = *(const bf16x8*)&As[buf][(wr * 64 + m * 16 + ra) * 32 + gp8];
#pragma unroll
    for (int n = 0; n < 4; n++)
      bfr[n] = *(const bf16x8*)&Bs[buf][(wc * 64 + n * 16 + ra) * 32 + gp8];
#pragma unroll
    for (int m = 0; m < 4; m++)
#pragma unroll
      for (int n = 0; n < 4; n++)
        acc[m][n] = __builtin_amdgcn_mfma_f32_16x16x32_bf16(af[m], bfr[n], acc[m][n], 0, 0, 0);
    buf ^= 1;
  }

  // epilogue: D lane layout col = lane&15, row = (lane>>4)*4 + i
  const int cr = (lane >> 4) * 4;
  const int cc = lane & 15;
#pragma unroll
  for (int m = 0; m < 4; m++) {
    int grow = rowA0 + wr * 64 + m * 16 + cr;
#pragma unroll
    for (int n = 0; n < 4; n++) {
      int gcol = colB0 + wc * 64 + n * 16 + cc;
      float bv = bias[gcol];
#pragma unroll
      for (int i = 0; i < 4; i++) {
        float v = acc[m][n][i] + bv;
        if (GELU) v = 0.5f * v * (1.f + erff(v * 0.70710678118654752f));
        C[(size_t)(grow + i) * N + gcol] = f2bf(v);
      }
    }
  }
}

// ---------------- small GEMM (M=10): C[10][1024] = A[10][1024] * Wt^T + bias ----------------
__global__ __launch_bounds__(256) void k_gemm10(const unsigned short* __restrict__ A,
                                                const unsigned short* __restrict__ Bt,
                                                const float* __restrict__ bias,
                                                unsigned short* __restrict__ C) {
  __shared__ float af[1024];
  int m = blockIdx.x, nb = blockIdx.y;
  int t = threadIdx.x;
#pragma unroll
  for (int i = 0; i < 4; i++) af[t * 4 + i] = bf2f(A[(size_t)m * 1024 + t * 4 + i]);
  __syncthreads();
  int w = t >> 6, lane = t & 63;
  for (int n = nb * 64 + w; n < nb * 64 + 64; n += 4) {
    const unsigned short* brow = Bt + (size_t)n * 1024 + lane * 16;
    float acc = 0.f;
#pragma unroll
    for (int j = 0; j < 16; j++) acc += af[lane * 16 + j] * bf2f(brow[j]);
#pragma unroll
    for (int o = 32; o; o >>= 1) acc += __shfl_xor(acc, o);
    if (lane == 0) C[(size_t)m * 1024 + n] = f2bf(acc + bias[n]);
  }
}

// ---------------- entmax-1.5 attention, MFMA version ----------------
// One block per (batch,head). QK^T via MFMA -> scores LDS (f32) -> register bisection
// (G lanes per row, group shfl_xor reduce) -> P bf16 in LDS -> PV via MFMA.
// Output in torch Hopfield "mix" layout: out[batch][h*(L/16)+l/16][(l%16)*64+e].
template <int L, int S, bool SHARED>
__global__ __launch_bounds__(256) void k_attn(const unsigned short* __restrict__ Q,
                                              const unsigned short* __restrict__ Kb,
                                              const unsigned short* __restrict__ Vb,
                                              unsigned short* __restrict__ Out) {
  constexpr int SP = (S <= 32) ? 32 : 64;  // S padded to MFMA K-multiple
  constexpr int QST = 72;                  // Q/K row stride (bf16), pad for bank spread
  constexpr int VST = SP + 8;              // Vt/P row stride
  constexpr int CST = SP + 4;              // scores row stride (f32)
  __shared__ unsigned short Qs[L * QST];   // reused as P (stride VST) in phase 3
  __shared__ unsigned short Ks[SP * QST];
  __shared__ unsigned short Vt[64 * VST];  // Vt[e][s] = V[s][e]
  __shared__ float Sc[L * CST];
  __shared__ float Rps[L];
  const int blk = blockIdx.x, batch = blk >> 4, h = blk & 15;
  const int t = threadIdx.x, w = t >> 6, lane = t & 63;

  // --- stage Q (16B chunks) ---
  for (int c = t; c < L * 8; c += 256) {
    int r = c >> 3, ch = (c & 7) * 8;
    *(i32x4*)&Qs[r * QST + ch] =
        *(const i32x4*)&Q[((size_t)(batch * L + r)) * 1024 + h * 64 + ch];
  }
  // --- stage K rows (zero rows >= S) ---
  for (int c = t; c < SP * 8; c += 256) {
    int r = c >> 3, ch = (c & 7) * 8;
    i32x4 v = {0, 0, 0, 0};
    if (r < S) {
      size_t rb = SHARED ? (size_t)r : (size_t)(batch * S + r);
      v = *(const i32x4*)&Kb[rb * 1024 + h * 64 + ch];
    }
    *(i32x4*)&Ks[r * QST + ch] = v;
  }
  // --- stage V transposed (zero cols >= S) ---
  for (int c = t; c < SP * 64; c += 256) {
    int s = c >> 6, e = c & 63;
    unsigned short v = 0;
    if (s < S) {
      size_t rb = SHARED ? (size_t)s : (size_t)(batch * S + s);
      v = Vb[rb * 1024 + h * 64 + e];
    }
    Vt[e * VST + s] = v;
  }
  __syncthreads();

  const int ka = (lane >> 4) * 8, ra = lane & 15;
  const int cr = (lane >> 4) * 4, cc = lane & 15;
  // --- phase 1: scores = (Q K^T) * 0.5/sqrt(64) ---
  constexpr int NT = SP / 16, TT = (L / 16) * NT;
  for (int tt = w; tt < TT; tt += 4) {
    int m = tt / NT, n = tt % NT;
    f32x4 a = {0.f, 0.f, 0.f, 0.f};
#pragma unroll
    for (int ks = 0; ks < 2; ks++) {  // E=64 -> 2 K-steps
      bf16x8 af = *(const bf16x8*)&Qs[(m * 16 + ra) * QST + ks * 32 + ka];
      bf16x8 bf = *(const bf16x8*)&Ks[(n * 16 + ra) * QST + ks * 32 + ka];
      a = __builtin_amdgcn_mfma_f32_16x16x32_bf16(af, bf, a, 0, 0, 0);
    }
#pragma unroll
    for (int i = 0; i < 4; i++)
      Sc[(m * 16 + cr + i) * CST + n * 16 + cc] = a[i] * 0.0625f;
  }
  __syncthreads();

  // --- phase 2: bisection, G lanes per row, scores in registers ---
  constexpr int G = 256 / L, RW = 64 / G, SL = SP / G;
  const int row = w * RW + lane / G, sub = lane % G;
  float xs[SL];
#pragma unroll
  for (int j = 0; j < SL; j++) {
    int s = sub * SL + j;
    float v = Sc[row * CST + s];
    if (S < SP && s >= S) v = -1e30f;
    xs[j] = v;
  }
  float mx = xs[0];
#pragma unroll
  for (int j = 1; j < SL; j++) mx = fmaxf(mx, xs[j]);
#pragma unroll
  for (int o = G / 2; o; o >>= 1) mx = fmaxf(mx, __shfl_xor(mx, o));
  const float hoff = (S == 64) ? 0.125f : (S == 32) ? 0.17677669529663687f : 0.31622776601683794f;
  float lo = mx - 1.f, hi = mx - hoff;
#pragma unroll 1
  for (int it = 0; it < 26; it++) {
    float mid = 0.5f * (lo + hi);
    float f = 0.f;
#pragma unroll
    for (int j = 0; j < SL; j++) { float dd = fmaxf(xs[j] - mid, 0.f); f += dd * dd; }
#pragma unroll
    for (int o = G / 2; o; o >>= 1) f += __shfl_xor(f, o);
    bool gt = f > 1.f;
    lo = gt ? mid : lo;
    hi = gt ? hi : mid;
  }
  float tau = 0.5f * (lo + hi);
  float ps = 0.f;
#pragma unroll
  for (int j = 0; j < SL; j++) { float dd = fmaxf(xs[j] - tau, 0.f); xs[j] = dd * dd; ps += xs[j]; }
#pragma unroll
  for (int o = G / 2; o; o >>= 1) ps += __shfl_xor(ps, o);
  if (sub == 0) Rps[row] = 1.f / ps;
  unsigned short* Pb = Qs;  // reuse Qs as P (unnormalized, bf16, stride VST)
#pragma unroll
  for (int j = 0; j < SL; j += 4) {
    u16x4 pv;
#pragma unroll
    for (int jj = 0; jj < 4; jj++) pv[jj] = f2bf(xs[j + jj]);
    *(u16x4*)&Pb[row * VST + sub * SL + j] = pv;
  }
  __syncthreads();

  // --- phase 3: out = (P . Vt^T) * Rps[row] ---
  constexpr int TT2 = (L / 16) * 4;
  for (int tt = w; tt < TT2; tt += 4) {
    int m = tt >> 2, n = tt & 3;
    f32x4 a = {0.f, 0.f, 0.f, 0.f};
#pragma unroll
    for (int ks = 0; ks < SP / 32; ks++) {
      bf16x8 af = *(const bf16x8*)&Pb[(m * 16 + ra) * VST + ks * 32 + ka];
      bf16x8 bf = *(const bf16x8*)&Vt[(n * 16 + ra) * VST + ks * 32 + ka];
      a = __builtin_amdgcn_mfma_f32_16x16x32_bf16(af, bf, a, 0, 0, 0);
    }
#pragma unroll
    for (int i = 0; i < 4; i++) {
      int l = m * 16 + cr + i, e = n * 16 + cc;
      float val = a[i] * Rps[l];
      int l_new = h * (L / 16) + (l >> 4);
      int cg = (l & 15) * 64 + e;
      Out[((size_t)(batch * L + l_new)) * 1024 + cg] = f2bf(val);
    }
  }
}

// ---------------- LayerNorm(a+b) * g + be, optional row permutation / f32 out ----------------
// MODE 0: orow=r. MODE 1: r=(b,t,s) dims(32,64) -> orow=(b,s,t). MODE 2: r=(b,s,t) dims(64,32) -> orow=(b,t,s).
template <int MODE, bool F32OUT>
__global__ __launch_bounds__(256) void k_ln(const unsigned short* __restrict__ a,
                                            const unsigned short* __restrict__ b,
                                            const float* __restrict__ g,
                                            const float* __restrict__ be,
                                            void* __restrict__ outp) {
  __shared__ float red[8];
  int r = blockIdx.x, t = threadIdx.x;
  size_t base = (size_t)r * 1024 + t * 4;
  u16x4 av = *(const u16x4*)(a + base);
  u16x4 bv = *(const u16x4*)(b + base);
  float x[4];
  float s = 0.f, ss = 0.f;
#pragma unroll
  for (int i = 0; i < 4; i++) {
    x[i] = bf2f(av[i]) + bf2f(bv[i]);
    s += x[i]; ss += x[i] * x[i];
  }
#pragma unroll
  for (int o = 32; o; o >>= 1) { s += __shfl_xor(s, o); ss += __shfl_xor(ss, o); }
  int w = t >> 6;
  if ((t & 63) == 0) { red[w] = s; red[4 + w] = ss; }
  __syncthreads();
  s = red[0] + red[1] + red[2] + red[3];
  ss = red[4] + red[5] + red[6] + red[7];
  float mean = s * (1.f / 1024.f);
  float var = ss * (1.f / 1024.f) - mean * mean;
  float rstd = rsqrtf(var + 1e-5f);
  int orow;
  if (MODE == 0) orow = r;
  else if (MODE == 1) { int bi = r >> 11, rem = r & 2047; int tt = rem >> 6, sd = rem & 63; orow = (bi << 11) + sd * 32 + tt; }
  else { int bi = r >> 11, rem = r & 2047; int sd = rem >> 5, tt = rem & 31; orow = (bi << 11) + tt * 64 + sd; }
  size_t ob = (size_t)orow * 1024 + t * 4;
  if (F32OUT) {
    f32x4 y;
#pragma unroll
    for (int i = 0; i < 4; i++) y[i] = (x[i] - mean) * rstd * g[t * 4 + i] + be[t * 4 + i];
    *(f32x4*)((float*)outp + ob) = y;
  } else {
    u16x4 y;
#pragma unroll
    for (int i = 0; i < 4; i++) y[i] = f2bf((x[i] - mean) * rstd * g[t * 4 + i] + be[t * 4 + i]);
    *(u16x4*)((unsigned short*)outp + ob) = y;
  }
}

// =======================================================================================

extern "C" void kernel_launch(void* const* d_in, const int* in_sizes, int n_in,
                              void* d_out, int out_size, void* d_ws, size_t ws_size,
                              hipStream_t stream) {
  // dims: b=8, ts_d=32, seg=64, d=1024, h=16, dff=4096, factor=10
  const int M = 16384;
  if (n_in < 43 || in_sizes[0] != 16777216 || in_sizes[25] != 10240 || in_sizes[34] != 4194304) {
    fprintf(stderr, "kernel_launch: unexpected input layout (n_in=%d s0=%d s25=%d s34=%d)\n",
            n_in, in_sizes[0], n_in > 25 ? in_sizes[25] : -1, n_in > 34 ? in_sizes[34] : -1);
    return;
  }
  const float* x = (const float*)d_in[0];
  const float* w[3][4]; const float* bia[3][4];
  for (int p = 0; p < 3; p++) {
    w[p][0] = (const float*)d_in[1 + 8 * p + 0]; bia[p][0] = (const float*)d_in[1 + 8 * p + 1];
    w[p][1] = (const float*)d_in[1 + 8 * p + 2]; bia[p][1] = (const float*)d_in[1 + 8 * p + 3];
    w[p][2] = (const float*)d_in[1 + 8 * p + 4]; bia[p][2] = (const float*)d_in[1 + 8 * p + 5];
    w[p][3] = (const float*)d_in[1 + 8 * p + 6]; bia[p][3] = (const float*)d_in[1 + 8 * p + 7];
  }
  const float* cs_key = (const float*)d_in[25];
  const float* ng[4]; const float* nb[4];
  for (int i = 0; i < 4; i++) { ng[i] = (const float*)d_in[26 + 2 * i]; nb[i] = (const float*)d_in[27 + 2 * i]; }
  const float* m_w1[2]; const float* m_b1[2]; const float* m_w2[2]; const float* m_b2[2];
  for (int i = 0; i < 2; i++) {
    m_w1[i] = (const float*)d_in[34 + 4 * i]; m_b1[i] = (const float*)d_in[35 + 4 * i];
    m_w2[i] = (const float*)d_in[36 + 4 * i]; m_b2[i] = (const float*)d_in[37 + 4 * i];
  }

  // ---- workspace bump allocator (budget 256 MiB; total used ~216 MiB) ----
  char* base = (char*)d_ws; size_t off = 0;
  auto alloc = [&](size_t bytes) -> void* {
    off = (off + 255) & ~(size_t)255;
    void* p = base + off; off += bytes; return p;
  };
  unsigned short* Wt[3][4];
  for (int p = 0; p < 3; p++)
    for (int j = 0; j < 4; j++) Wt[p][j] = (unsigned short*)alloc((size_t)1024 * 1024 * 2);
  unsigned short* Wm1u = (unsigned short*)alloc((size_t)4096 * 1024 * 2);
  unsigned short* Wm1d = (unsigned short*)alloc((size_t)1024 * 4096 * 2);
  unsigned short* Wm2u = (unsigned short*)alloc((size_t)4096 * 1024 * 2);
  unsigned short* Wm2d = (unsigned short*)alloc((size_t)1024 * 4096 * 2);
  // A[0..4]: 32 MiB each, CONTIGUOUS (bump keeps 32MiB blocks adjacent; 256-aligned sizes)
  unsigned short* A[5];
  for (int i = 0; i < 5; i++) A[i] = (unsigned short*)alloc((size_t)M * 1024 * 2);
  unsigned short* KeyB = (unsigned short*)alloc((size_t)10 * 1024 * 2);
  unsigned short* Kcs = (unsigned short*)alloc((size_t)10 * 1024 * 2);
  unsigned short* Vcs = (unsigned short*)alloc((size_t)10 * 1024 * 2);
  if (off > ws_size) {
    fprintf(stderr, "kernel_launch: ws too small: need %zu have %zu\n", off, ws_size);
    return;
  }
  const int MC = 8192;                 // MLP M-chunk rows
  unsigned short* HbT = A[0];          // 64 MiB scratch = A0+A1 region (dead during stage-T MLP)
  unsigned short* HbS = A[1];          // 64 MiB scratch = A1+A2 region (dead during stage-S MLP)

  auto gemm = [&](const unsigned short* Ap, const unsigned short* Bt, const float* bi,
                  unsigned short* Cp, int Mm, int Nn, int Kk, bool gelu) {
    dim3 g(Nn / 128, Mm / 128);
    if (gelu) k_gemm<true><<<g, 256, 0, stream>>>(Ap, Bt, bi, Cp, Mm, Nn, Kk);
    else      k_gemm<false><<<g, 256, 0, stream>>>(Ap, Bt, bi, Cp, Mm, Nn, Kk);
  };

  // ---- weight prep ----
  for (int p = 0; p < 3; p++)
    for (int j = 0; j < 4; j++)
      k_tcast<<<dim3(32, 32), 256, 0, stream>>>(w[p][j], Wt[p][j], 1024, 1024);
  k_tcast<<<dim3(128, 32), 256, 0, stream>>>(m_w1[0], Wm1u, 1024, 4096);
  k_tcast<<<dim3(32, 128), 256, 0, stream>>>(m_w2[0], Wm1d, 4096, 1024);
  k_tcast<<<dim3(128, 32), 256, 0, stream>>>(m_w1[1], Wm2u, 1024, 4096);
  k_tcast<<<dim3(32, 128), 256, 0, stream>>>(m_w2[1], Wm2d, 4096, 1024);
  k_cast<<<16384, 256, 0, stream>>>(x, A[0], 16777216 / 4);
  k_cast<<<10, 256, 0, stream>>>(cs_key, KeyB, 10240 / 4);

  // ---- stage T (time attention over seg; 256 batches, L=S=64) ----
  gemm(A[0], Wt[0][1], bia[0][1], A[1], M, 1024, 1024, false);             // K
  gemm(A[0], Wt[0][0], bia[0][0], A[2], M, 1024, 1024, false);             // Q
  gemm(A[1], Wt[0][2], bia[0][2], A[3], M, 1024, 1024, false);             // V = K@wv+bv
  k_attn<64, 64, false><<<256 * 16, 256, 0, stream>>>(A[2], A[1], A[3], A[4]);
  gemm(A[4], Wt[0][3], bia[0][3], A[1], M, 1024, 1024, false);             // time_enc
  k_ln<0, false><<<M, 256, 0, stream>>>(A[0], A[1], ng[0], nb[0], A[2]);   // D = LN(x+enc)
  for (int c = 0; c < M; c += MC) {                                        // R = mlp(D) -> A4
    gemm(A[2] + (size_t)c * 1024, Wm1u, m_b1[0], HbT, MC, 4096, 1024, true);
    gemm(HbT, Wm1d, m_b2[0], A[4] + (size_t)c * 1024, MC, 1024, 4096, false);
  }
  k_ln<1, false><<<M, 256, 0, stream>>>(A[2], A[4], ng[1], nb[1], A[3]);   // S = permute(LN(D+R))

  // ---- stage S (512 batches, L=32) ----
  k_gemm10<<<dim3(10, 16), 256, 0, stream>>>(KeyB, Wt[1][1], bia[1][1], Kcs);
  k_gemm10<<<dim3(10, 16), 256, 0, stream>>>(Kcs, Wt[1][2], bia[1][2], Vcs);
  gemm(A[3], Wt[1][0], bia[1][0], A[0], M, 1024, 1024, false);             // Qcs
  k_attn<32, 10, true><<<512 * 16, 256, 0, stream>>>(A[0], Kcs, Vcs, A[1]);
  gemm(A[1], Wt[1][3], bia[1][3], A[2], M, 1024, 1024, false);             // SH
  gemm(A[3], Wt[2][1], bia[2][1], A[0], M, 1024, 1024, false);             // Khp
  gemm(A[3], Wt[2][0], bia[2][0], A[1], M, 1024, 1024, false);             // Qhp
  gemm(A[0], Wt[2][2], bia[2][2], A[4], M, 1024, 1024, false);             // Vhp
  k_attn<32, 32, false><<<512 * 16, 256, 0, stream>>>(A[1], A[0], A[4], A[3]);
  gemm(A[3], Wt[2][3], bia[2][3], A[1], M, 1024, 1024, false);             // PH
  k_ln<0, false><<<M, 256, 0, stream>>>(A[2], A[1], ng[2], nb[2], A[0]);   // DE = LN(SH+PH)
  for (int c = 0; c < M; c += MC) {                                        // mlp2 -> A3
    gemm(A[0] + (size_t)c * 1024, Wm2u, m_b1[1], HbS, MC, 4096, 1024, true);
    gemm(HbS, Wm2d, m_b2[1], A[3] + (size_t)c * 1024, MC, 1024, 4096, false);
  }
  k_ln<2, true><<<M, 256, 0, stream>>>(A[0], A[3], ng[3], nb[3], d_out);   // final LN+permute, f32
}

// Round 5
// 1609.163 us; speedup vs baseline: 2.3664x; 1.0276x over previous
//
#include <hip/hip_runtime.h>
#include <cstdio>

typedef __bf16 bf16x8 __attribute__((ext_vector_type(8)));
typedef float f32x4 __attribute__((ext_vector_type(4)));
typedef int i32x4 __attribute__((ext_vector_type(4)));
typedef unsigned short u16x4 __attribute__((ext_vector_type(4)));

__device__ __forceinline__ float bf2f(unsigned short u) {
  union { unsigned int i; float f; } x; x.i = ((unsigned int)u) << 16; return x.f;
}
__device__ __forceinline__ unsigned short f2bf(float f) {
  union { float f; unsigned int i; } x; x.f = f;
  unsigned int r = x.i + 0x7fffu + ((x.i >> 16) & 1u);
  return (unsigned short)(r >> 16);
}

// async global->LDS, 16B per lane; LDS dest is wave-uniform base + lane*16
__device__ __forceinline__ void gl2lds16(const unsigned short* g, unsigned short* l) {
  __builtin_amdgcn_global_load_lds((const __attribute__((address_space(1))) unsigned int*)g,
                                   (__attribute__((address_space(3))) unsigned int*)l, 16, 0, 0);
}

// ---------------- elementwise f32 -> bf16 cast (vec4) ----------------
__global__ __launch_bounds__(256) void k_cast(const float* __restrict__ in,
                                              unsigned short* __restrict__ out, int n4) {
  int i = blockIdx.x * 256 + threadIdx.x;
  if (i >= n4) return;
  f32x4 v = ((const f32x4*)in)[i];
  u16x4 o;
  o[0] = f2bf(v[0]); o[1] = f2bf(v[1]); o[2] = f2bf(v[2]); o[3] = f2bf(v[3]);
  ((u16x4*)out)[i] = o;
}

// -------- transpose-cast: src f32 [K][N] -> dst bf16 [N][K] --------
__global__ __launch_bounds__(256) void k_tcast(const float* __restrict__ src,
                                               unsigned short* __restrict__ dst,
                                               int K, int N) {
  __shared__ float tile[32][33];
  int gx = blockIdx.x * 32;  // N dim
  int gy = blockIdx.y * 32;  // K dim
  int t = threadIdx.x;
  int c = t & 31, r0 = t >> 5;
#pragma unroll
  for (int i = 0; i < 4; i++) {
    int r = r0 + i * 8;
    tile[r][c] = src[(size_t)(gy + r) * N + gx + c];
  }
  __syncthreads();
#pragma unroll
  for (int i = 0; i < 4; i++) {
    int r = r0 + i * 8;
    dst[(size_t)(gx + r) * K + gy + c] = f2bf(tile[c][r]);
  }
}

// ============ MFMA GEMM, 8-phase-family structure ============
// C[M][N] = A[M][K](bf16 rm) * Bt[N][K]^T + bias (opt exact GELU).
// Tile BM x 256, BK=64, 512 threads = 8 waves (2m x 4n); wave tile (BM/2) x 64.
// 4 phases/K-tile: {ds_read subtile; [stage next tile @p0]; barrier; setprio(1);
// MFMA quadrant; setprio(0); barrier}. Correctness sync = boundary vmcnt(0)+barrier only
// (buf[cur] is stable across all 4 phases; staging targets buf^1).
// T2: LDS linear [R][64]; global source granule pre-XOR'd by (row&7); frag reads XOR back.
template <int BM, bool GELU>
__global__ __launch_bounds__(512, 2) void k_gemm2(const unsigned short* __restrict__ Ag,
                                                  const unsigned short* __restrict__ Btg,
                                                  const float* __restrict__ bias,
                                                  unsigned short* __restrict__ C,
                                                  int M, int N, int K) {
  constexpr int RPW = BM / 2;   // rows per wave tile (128 or 64)
  constexpr int RF = RPW / 16;  // row frags per wave (8 or 4)
  constexpr int RPP = RF / 2;   // row frags per phase (4 or 2)
  __shared__ unsigned short As[2][BM * 64];
  __shared__ unsigned short Bs[2][256 * 64];
  // T1: XCD-aware bijective block swizzle (grids here are multiples of 8)
  int nwg = gridDim.x * gridDim.y;
  int lin = blockIdx.y * gridDim.x + blockIdx.x;
  int swz = (nwg & 7) ? lin : ((lin & 7) * (nwg >> 3) + (lin >> 3));
  const int rowA0 = (swz / gridDim.x) * BM, colB0 = (swz % gridDim.x) * 256;
  const int t = threadIdx.x, w = t >> 6, lane = t & 63;
  const int wm = w >> 2, wn = w & 3;
  const int g = lane >> 4, ra = lane & 15;
  // T2 read-side: elem offset within row for k-step 0/1, XOR'd by (row&7)<<3
  const int xorE = (ra & 7) << 3;
  const int koff0 = (g * 8) ^ xorE;
  const int koff1 = (32 | (g * 8)) ^ xorE;
  // staging source (write-side inverse swizzle): lane covers row (l>>3), granule (l&7)^(l>>3)
  const int srow8 = lane >> 3;
  const int scol = ((lane & 7) ^ srow8) * 8;

  f32x4 acc[RF][4] = {};

  auto stage = [&](int buf, int kk) {
#pragma unroll
    for (int i = 0; i < BM / 64; i++) {
      int rbase = (w + i * 8) * 8;  // 8-row (1KB) slice per wave-instruction
      gl2lds16(Ag + (size_t)(rowA0 + rbase + srow8) * K + kk + scol, &As[buf][rbase * 64]);
    }
#pragma unroll
    for (int i = 0; i < 4; i++) {
      int rbase = (w + i * 8) * 8;
      gl2lds16(Btg + (size_t)(colB0 + rbase + srow8) * K + kk + scol, &Bs[buf][rbase * 64]);
    }
  };

  stage(0, 0);
  asm volatile("s_waitcnt vmcnt(0)" ::: "memory");
  __builtin_amdgcn_s_barrier();

  const int NT = K / 64;
  int buf = 0;
  bf16x8 afr[RPP][2], bfr[4][2];
  for (int tt = 0; tt < NT; ++tt) {
    const unsigned short* Ab = &As[buf][0];
    const unsigned short* Bb = &Bs[buf][0];
    // ---- phase 0: A rf[0..RPP), B cf[0,1]; stage next; MFMA quad(0, c0-1)
#pragma unroll
    for (int r = 0; r < RPP; r++) {
      int lr = wm * RPW + r * 16 + ra;
      afr[r][0] = *(const bf16x8*)&Ab[lr * 64 + koff0];
      afr[r][1] = *(const bf16x8*)&Ab[lr * 64 + koff1];
    }
#pragma unroll
    for (int c = 0; c < 2; c++) {
      int nr = wn * 64 + c * 16 + ra;
      bfr[c][0] = *(const bf16x8*)&Bb[nr * 64 + koff0];
      bfr[c][1] = *(const bf16x8*)&Bb[nr * 64 + koff1];
    }
    if (tt + 1 < NT) stage(buf ^ 1, (tt + 1) * 64);
    __builtin_amdgcn_s_barrier();
    __builtin_amdgcn_s_setprio(1);
#pragma unroll
    for (int r = 0; r < RPP; r++)
#pragma unroll
      for (int c = 0; c < 2; c++)
#pragma unroll
        for (int ks = 0; ks < 2; ks++)
          acc[r][c] = __builtin_amdgcn_mfma_f32_16x16x32_bf16(afr[r][ks], bfr[c][ks], acc[r][c], 0, 0, 0);
    __builtin_amdgcn_s_setprio(0);
    __builtin_amdgcn_s_barrier();
    // ---- phase 1: B cf[2,3]; MFMA quad(0, c2-3)
#pragma unroll
    for (int c = 2; c < 4; c++) {
      int nr = wn * 64 + c * 16 + ra;
      bfr[c][0] = *(const bf16x8*)&Bb[nr * 64 + koff0];
      bfr[c][1] = *(const bf16x8*)&Bb[nr * 64 + koff1];
    }
    __builtin_amdgcn_s_barrier();
    __builtin_amdgcn_s_setprio(1);
#pragma unroll
    for (int r = 0; r < RPP; r++)
#pragma unroll
      for (int c = 2; c < 4; c++)
#pragma unroll
        for (int ks = 0; ks < 2; ks++)
          acc[r][c] = __builtin_amdgcn_mfma_f32_16x16x32_bf16(afr[r][ks], bfr[c][ks], acc[r][c], 0, 0, 0);
    __builtin_amdgcn_s_setprio(0);
    __builtin_amdgcn_s_barrier();
    // ---- phase 2: A rf[RPP..RF); MFMA quad(1, c0-1)
#pragma unroll
    for (int r = 0; r < RPP; r++) {
      int lr = wm * RPW + (RPP + r) * 16 + ra;
      afr[r][0] = *(const bf16x8*)&Ab[lr * 64 + koff0];
      afr[r][1] = *(const bf16x8*)&Ab[lr * 64 + koff1];
    }
    __builtin_amdgcn_s_barrier();
    __builtin_amdgcn_s_setprio(1);
#pragma unroll
    for (int r = 0; r < RPP; r++)
#pragma unroll
      for (int c = 0; c < 2; c++)
#pragma unroll
        for (int ks = 0; ks < 2; ks++)
          acc[RPP + r][c] = __builtin_amdgcn_mfma_f32_16x16x32_bf16(afr[r][ks], bfr[c][ks], acc[RPP + r][c], 0, 0, 0);
    __builtin_amdgcn_s_setprio(0);
    __builtin_amdgcn_s_barrier();
    // ---- phase 3: MFMA quad(1, c2-3); tile boundary drain
    __builtin_amdgcn_s_setprio(1);
#pragma unroll
    for (int r = 0; r < RPP; r++)
#pragma unroll
      for (int c = 2; c < 4; c++)
#pragma unroll
        for (int ks = 0; ks < 2; ks++)
          acc[RPP + r][c] = __builtin_amdgcn_mfma_f32_16x16x32_bf16(afr[r][ks], bfr[c][ks], acc[RPP + r][c], 0, 0, 0);
    __builtin_amdgcn_s_setprio(0);
    asm volatile("s_waitcnt vmcnt(0)" ::: "memory");
    __builtin_amdgcn_s_barrier();
    buf ^= 1;
  }

  // epilogue: D lane layout col = lane&15, row = (lane>>4)*4 + i
  const int cr = g * 4, cc = ra;
#pragma unroll
  for (int r = 0; r < RF; r++) {
    int grow = rowA0 + wm * RPW + r * 16 + cr;
#pragma unroll
    for (int c = 0; c < 4; c++) {
      int gcol = colB0 + wn * 64 + c * 16 + cc;
      float bv = bias[gcol];
#pragma unroll
      for (int i = 0; i < 4; i++) {
        float v = acc[r][c][i] + bv;
        if (GELU) v = 0.5f * v * (1.f + erff(v * 0.70710678118654752f));
        C[(size_t)(grow + i) * N + gcol] = f2bf(v);
      }
    }
  }
}

// ---------------- small GEMM (M=10): C[10][1024] = A[10][1024] * Wt^T + bias ----------------
__global__ __launch_bounds__(256) void k_gemm10(const unsigned short* __restrict__ A,
                                                const unsigned short* __restrict__ Bt,
                                                const float* __restrict__ bias,
                                                unsigned short* __restrict__ C) {
  __shared__ float af[1024];
  int m = blockIdx.x, nb = blockIdx.y;
  int t = threadIdx.x;
#pragma unroll
  for (int i = 0; i < 4; i++) af[t * 4 + i] = bf2f(A[(size_t)m * 1024 + t * 4 + i]);
  __syncthreads();
  int w = t >> 6, lane = t & 63;
  for (int n = nb * 64 + w; n < nb * 64 + 64; n += 4) {
    const unsigned short* brow = Bt + (size_t)n * 1024 + lane * 16;
    float acc = 0.f;
#pragma unroll
    for (int j = 0; j < 16; j++) acc += af[lane * 16 + j] * bf2f(brow[j]);
#pragma unroll
    for (int o = 32; o; o >>= 1) acc += __shfl_xor(acc, o);
    if (lane == 0) C[(size_t)m * 1024 + n] = f2bf(acc + bias[n]);
  }
}

// ---------------- entmax-1.5 attention, MFMA version ----------------
// One block per (batch,head). QK^T via MFMA -> scores LDS (f32) -> register bisection
// (G lanes per row, group shfl_xor reduce) -> P bf16 in LDS -> PV via MFMA.
// Output in torch Hopfield "mix" layout: out[batch][h*(L/16)+l/16][(l%16)*64+e].
template <int L, int S, bool SHARED>
__global__ __launch_bounds__(256) void k_attn(const unsigned short* __restrict__ Q,
                                              const unsigned short* __restrict__ Kb,
                                              const unsigned short* __restrict__ Vb,
                                              unsigned short* __restrict__ Out) {
  constexpr int SP = (S <= 32) ? 32 : 64;  // S padded to MFMA K-multiple
  constexpr int QST = 72;                  // Q/K row stride (bf16), pad for bank spread
  constexpr int VST = SP + 8;              // Vt/P row stride
  constexpr int CST = SP + 4;              // scores row stride (f32)
  __shared__ unsigned short Qs[L * QST];   // reused as P (stride VST) in phase 3
  __shared__ unsigned short Ks[SP * QST];
  __shared__ unsigned short Vt[64 * VST];  // Vt[e][s] = V[s][e]
  __shared__ float Sc[L * CST];
  __shared__ float Rps[L];
  const int blk = blockIdx.x, batch = blk >> 4, h = blk & 15;
  const int t = threadIdx.x, w = t >> 6, lane = t & 63;

  // --- stage Q (16B chunks) ---
  for (int c = t; c < L * 8; c += 256) {
    int r = c >> 3, ch = (c & 7) * 8;
    *(i32x4*)&Qs[r * QST + ch] =
        *(const i32x4*)&Q[((size_t)(batch * L + r)) * 1024 + h * 64 + ch];
  }
  // --- stage K rows (zero rows >= S) ---
  for (int c = t; c < SP * 8; c += 256) {
    int r = c >> 3, ch = (c & 7) * 8;
    i32x4 v = {0, 0, 0, 0};
    if (r < S) {
      size_t rb = SHARED ? (size_t)r : (size_t)(batch * S + r);
      v = *(const i32x4*)&Kb[rb * 1024 + h * 64 + ch];
    }
    *(i32x4*)&Ks[r * QST + ch] = v;
  }
  // --- stage V transposed (zero cols >= S) ---
  for (int c = t; c < SP * 64; c += 256) {
    int s = c >> 6, e = c & 63;
    unsigned short v = 0;
    if (s < S) {
      size_t rb = SHARED ? (size_t)s : (size_t)(batch * S + s);
      v = Vb[rb * 1024 + h * 64 + e];
    }
    Vt[e * VST + s] = v;
  }
  __syncthreads();

  const int ka = (lane >> 4) * 8, ra = lane & 15;
  const int cr = (lane >> 4) * 4, cc = lane & 15;
  // --- phase 1: scores = (Q K^T) * 0.5/sqrt(64) ---
  constexpr int NT = SP / 16, TT = (L / 16) * NT;
  for (int tt = w; tt < TT; tt += 4) {
    int m = tt / NT, n = tt % NT;
    f32x4 a = {0.f, 0.f, 0.f, 0.f};
#pragma unroll
    for (int ks = 0; ks < 2; ks++) {  // E=64 -> 2 K-steps
      bf16x8 af = *(const bf16x8*)&Qs[(m * 16 + ra) * QST + ks * 32 + ka];
      bf16x8 bf = *(const bf16x8*)&Ks[(n * 16 + ra) * QST + ks * 32 + ka];
      a = __builtin_amdgcn_mfma_f32_16x16x32_bf16(af, bf, a, 0, 0, 0);
    }
#pragma unroll
    for (int i = 0; i < 4; i++)
      Sc[(m * 16 + cr + i) * CST + n * 16 + cc] = a[i] * 0.0625f;
  }
  __syncthreads();

  // --- phase 2: bisection, G lanes per row, scores in registers ---
  constexpr int G = 256 / L, RW = 64 / G, SL = SP / G;
  const int row = w * RW + lane / G, sub = lane % G;
  float xs[SL];
#pragma unroll
  for (int j = 0; j < SL; j++) {
    int s = sub * SL + j;
    float v = Sc[row * CST + s];
    if (S < SP && s >= S) v = -1e30f;
    xs[j] = v;
  }
  float mx = xs[0];
#pragma unroll
  for (int j = 1; j < SL; j++) mx = fmaxf(mx, xs[j]);
#pragma unroll
  for (int o = G / 2; o; o >>= 1) mx = fmaxf(mx, __shfl_xor(mx, o));
  const float hoff = (S == 64) ? 0.125f : (S == 32) ? 0.17677669529663687f : 0.31622776601683794f;
  float lo = mx - 1.f, hi = mx - hoff;
#pragma unroll 1
  for (int it = 0; it < 26; it++) {
    float mid = 0.5f * (lo + hi);
    float f = 0.f;
#pragma unroll
    for (int j = 0; j < SL; j++) { float dd = fmaxf(xs[j] - mid, 0.f); f += dd * dd; }
#pragma unroll
    for (int o = G / 2; o; o >>= 1) f += __shfl_xor(f, o);
    bool gt = f > 1.f;
    lo = gt ? mid : lo;
    hi = gt ? hi : mid;
  }
  float tau = 0.5f * (lo + hi);
  float ps = 0.f;
#pragma unroll
  for (int j = 0; j < SL; j++) { float dd = fmaxf(xs[j] - tau, 0.f); xs[j] = dd * dd; ps += xs[j]; }
#pragma unroll
  for (int o = G / 2; o; o >>= 1) ps += __shfl_xor(ps, o);
  if (sub == 0) Rps[row] = 1.f / ps;
  unsigned short* Pb = Qs;  // reuse Qs as P (unnormalized, bf16, stride VST)
#pragma unroll
  for (int j = 0; j < SL; j += 4) {
    u16x4 pv;
#pragma unroll
    for (int jj = 0; jj < 4; jj++) pv[jj] = f2bf(xs[j + jj]);
    *(u16x4*)&Pb[row * VST + sub * SL + j] = pv;
  }
  __syncthreads();

  // --- phase 3: out = (P . Vt^T) * Rps[row] ---
  constexpr int TT2 = (L / 16) * 4;
  for (int tt = w; tt < TT2; tt += 4) {
    int m = tt >> 2, n = tt & 3;
    f32x4 a = {0.f, 0.f, 0.f, 0.f};
#pragma unroll
    for (int ks = 0; ks < SP / 32; ks++) {
      bf16x8 af = *(const bf16x8*)&Pb[(m * 16 + ra) * VST + ks * 32 + ka];
      bf16x8 bf = *(const bf16x8*)&Vt[(n * 16 + ra) * VST + ks * 32 + ka];
      a = __builtin_amdgcn_mfma_f32_16x16x32_bf16(af, bf, a, 0, 0, 0);
    }
#pragma unroll
    for (int i = 0; i < 4; i++) {
      int l = m * 16 + cr + i, e = n * 16 + cc;
      float val = a[i] * Rps[l];
      int l_new = h * (L / 16) + (l >> 4);
      int cg = (l & 15) * 64 + e;
      Out[((size_t)(batch * L + l_new)) * 1024 + cg] = f2bf(val);
    }
  }
}

// ---------------- LayerNorm(a+b) * g + be, optional row permutation / f32 out ----------------
// MODE 0: orow=r. MODE 1: r=(b,t,s) dims(32,64) -> orow=(b,s,t). MODE 2: r=(b,s,t) dims(64,32) -> orow=(b,t,s).
template <int MODE, bool F32OUT>
__global__ __launch_bounds__(256) void k_ln(const unsigned short* __restrict__ a,
                                            const unsigned short* __restrict__ b,
                                            const float* __restrict__ g,
                                            const float* __restrict__ be,
                                            void* __restrict__ outp) {
  __shared__ float red[8];
  int r = blockIdx.x, t = threadIdx.x;
  size_t base = (size_t)r * 1024 + t * 4;
  u16x4 av = *(const u16x4*)(a + base);
  u16x4 bv = *(const u16x4*)(b + base);
  float x[4];
  float s = 0.f, ss = 0.f;
#pragma unroll
  for (int i = 0; i < 4; i++) {
    x[i] = bf2f(av[i]) + bf2f(bv[i]);
    s += x[i]; ss += x[i] * x[i];
  }
#pragma unroll
  for (int o = 32; o; o >>= 1) { s += __shfl_xor(s, o); ss += __shfl_xor(ss, o); }
  int w = t >> 6;
  if ((t & 63) == 0) { red[w] = s; red[4 + w] = ss; }
  __syncthreads();
  s = red[0] + red[1] + red[2] + red[3];
  ss = red[4] + red[5] + red[6] + red[7];
  float mean = s * (1.f / 1024.f);
  float var = ss * (1.f / 1024.f) - mean * mean;
  float rstd = rsqrtf(var + 1e-5f);
  int orow;
  if (MODE == 0) orow = r;
  else if (MODE == 1) { int bi = r >> 11, rem = r & 2047; int tt = rem >> 6, sd = rem & 63; orow = (bi << 11) + sd * 32 + tt; }
  else { int bi = r >> 11, rem = r & 2047; int sd = rem >> 5, tt = rem & 31; orow = (bi << 11) + tt * 64 + sd; }
  size_t ob = (size_t)orow * 1024 + t * 4;
  if (F32OUT) {
    f32x4 y;
#pragma unroll
    for (int i = 0; i < 4; i++) y[i] = (x[i] - mean) * rstd * g[t * 4 + i] + be[t * 4 + i];
    *(f32x4*)((float*)outp + ob) = y;
  } else {
    u16x4 y;
#pragma unroll
    for (int i = 0; i < 4; i++) y[i] = f2bf((x[i] - mean) * rstd * g[t * 4 + i] + be[t * 4 + i]);
    *(u16x4*)((unsigned short*)outp + ob) = y;
  }
}

// =======================================================================================

extern "C" void kernel_launch(void* const* d_in, const int* in_sizes, int n_in,
                              void* d_out, int out_size, void* d_ws, size_t ws_size,
                              hipStream_t stream) {
  // dims: b=8, ts_d=32, seg=64, d=1024, h=16, dff=4096, factor=10
  const int M = 16384;
  if (n_in < 43 || in_sizes[0] != 16777216 || in_sizes[25] != 10240 || in_sizes[34] != 4194304) {
    fprintf(stderr, "kernel_launch: unexpected input layout (n_in=%d s0=%d s25=%d s34=%d)\n",
            n_in, in_sizes[0], n_in > 25 ? in_sizes[25] : -1, n_in > 34 ? in_sizes[34] : -1);
    return;
  }
  const float* x = (const float*)d_in[0];
  const float* w[3][4]; const float* bia[3][4];
  for (int p = 0; p < 3; p++) {
    w[p][0] = (const float*)d_in[1 + 8 * p + 0]; bia[p][0] = (const float*)d_in[1 + 8 * p + 1];
    w[p][1] = (const float*)d_in[1 + 8 * p + 2]; bia[p][1] = (const float*)d_in[1 + 8 * p + 3];
    w[p][2] = (const float*)d_in[1 + 8 * p + 4]; bia[p][2] = (const float*)d_in[1 + 8 * p + 5];
    w[p][3] = (const float*)d_in[1 + 8 * p + 6]; bia[p][3] = (const float*)d_in[1 + 8 * p + 7];
  }
  const float* cs_key = (const float*)d_in[25];
  const float* ng[4]; const float* nb[4];
  for (int i = 0; i < 4; i++) { ng[i] = (const float*)d_in[26 + 2 * i]; nb[i] = (const float*)d_in[27 + 2 * i]; }
  const float* m_w1[2]; const float* m_b1[2]; const float* m_w2[2]; const float* m_b2[2];
  for (int i = 0; i < 2; i++) {
    m_w1[i] = (const float*)d_in[34 + 4 * i]; m_b1[i] = (const float*)d_in[35 + 4 * i];
    m_w2[i] = (const float*)d_in[36 + 4 * i]; m_b2[i] = (const float*)d_in[37 + 4 * i];
  }

  // ---- workspace bump allocator (budget 256 MiB; total used ~216 MiB) ----
  char* base = (char*)d_ws; size_t off = 0;
  auto alloc = [&](size_t bytes) -> void* {
    off = (off + 255) & ~(size_t)255;
    void* p = base + off; off += bytes; return p;
  };
  unsigned short* Wt[3][4];
  for (int p = 0; p < 3; p++)
    for (int j = 0; j < 4; j++) Wt[p][j] = (unsigned short*)alloc((size_t)1024 * 1024 * 2);
  unsigned short* Wm1u = (unsigned short*)alloc((size_t)4096 * 1024 * 2);
  unsigned short* Wm1d = (unsigned short*)alloc((size_t)1024 * 4096 * 2);
  unsigned short* Wm2u = (unsigned short*)alloc((size_t)4096 * 1024 * 2);
  unsigned short* Wm2d = (unsigned short*)alloc((size_t)1024 * 4096 * 2);
  unsigned short* A[5];
  for (int i = 0; i < 5; i++) A[i] = (unsigned short*)alloc((size_t)M * 1024 * 2);
  unsigned short* KeyB = (unsigned short*)alloc((size_t)10 * 1024 * 2);
  unsigned short* Kcs = (unsigned short*)alloc((size_t)10 * 1024 * 2);
  unsigned short* Vcs = (unsigned short*)alloc((size_t)10 * 1024 * 2);
  if (off > ws_size) {
    fprintf(stderr, "kernel_launch: ws too small: need %zu have %zu\n", off, ws_size);
    return;
  }
  const int MC = 8192;                 // MLP M-chunk rows
  unsigned short* HbT = A[0];          // 64 MiB scratch = A0+A1 region (dead during stage-T MLP)
  unsigned short* HbS = A[1];          // 64 MiB scratch = A1+A2 region (dead during stage-S MLP)

  // BM=256 for N%256==0 or tall-M cases; BM=128 keeps grid >= 256 for N=1024, M=8192
  auto gemm = [&](const unsigned short* Ap, const unsigned short* Bt, const float* bi,
                  unsigned short* Cp, int Mm, int Nn, int Kk, bool gelu, bool bm128) {
    if (bm128) {
      dim3 g(Nn / 256, Mm / 128);
      if (gelu) k_gemm2<128, true><<<g, 512, 0, stream>>>(Ap, Bt, bi, Cp, Mm, Nn, Kk);
      else      k_gemm2<128, false><<<g, 512, 0, stream>>>(Ap, Bt, bi, Cp, Mm, Nn, Kk);
    } else {
      dim3 g(Nn / 256, Mm / 256);
      if (gelu) k_gemm2<256, true><<<g, 512, 0, stream>>>(Ap, Bt, bi, Cp, Mm, Nn, Kk);
      else      k_gemm2<256, false><<<g, 512, 0, stream>>>(Ap, Bt, bi, Cp, Mm, Nn, Kk);
    }
  };

  // ---- weight prep ----
  for (int p = 0; p < 3; p++)
    for (int j = 0; j < 4; j++)
      k_tcast<<<dim3(32, 32), 256, 0, stream>>>(w[p][j], Wt[p][j], 1024, 1024);
  k_tcast<<<dim3(128, 32), 256, 0, stream>>>(m_w1[0], Wm1u, 1024, 4096);
  k_tcast<<<dim3(32, 128), 256, 0, stream>>>(m_w2[0], Wm1d, 4096, 1024);
  k_tcast<<<dim3(128, 32), 256, 0, stream>>>(m_w1[1], Wm2u, 1024, 4096);
  k_tcast<<<dim3(32, 128), 256, 0, stream>>>(m_w2[1], Wm2d, 4096, 1024);
  k_cast<<<16384, 256, 0, stream>>>(x, A[0], 16777216 / 4);
  k_cast<<<10, 256, 0, stream>>>(cs_key, KeyB, 10240 / 4);

  // ---- stage T (time attention over seg; 256 batches, L=S=64) ----
  gemm(A[0], Wt[0][1], bia[0][1], A[1], M, 1024, 1024, false, false);      // K
  gemm(A[0], Wt[0][0], bia[0][0], A[2], M, 1024, 1024, false, false);      // Q
  gemm(A[1], Wt[0][2], bia[0][2], A[3], M, 1024, 1024, false, false);      // V = K@wv+bv
  k_attn<64, 64, false><<<256 * 16, 256, 0, stream>>>(A[2], A[1], A[3], A[4]);
  gemm(A[4], Wt[0][3], bia[0][3], A[1], M, 1024, 1024, false, false);      // time_enc
  k_ln<0, false><<<M, 256, 0, stream>>>(A[0], A[1], ng[0], nb[0], A[2]);   // D = LN(x+enc)
  for (int c = 0; c < M; c += MC) {                                        // R = mlp(D) -> A4
    gemm(A[2] + (size_t)c * 1024, Wm1u, m_b1[0], HbT, MC, 4096, 1024, true, false);
    gemm(HbT, Wm1d, m_b2[0], A[4] + (size_t)c * 1024, MC, 1024, 4096, false, true);
  }
  k_ln<1, false><<<M, 256, 0, stream>>>(A[2], A[4], ng[1], nb[1], A[3]);   // S = permute(LN(D+R))

  // ---- stage S (512 batches, L=32) ----
  k_gemm10<<<dim3(10, 16), 256, 0, stream>>>(KeyB, Wt[1][1], bia[1][1], Kcs);
  k_gemm10<<<dim3(10, 16), 256, 0, stream>>>(Kcs, Wt[1][2], bia[1][2], Vcs);
  gemm(A[3], Wt[1][0], bia[1][0], A[0], M, 1024, 1024, false, false);      // Qcs
  k_attn<32, 10, true><<<512 * 16, 256, 0, stream>>>(A[0], Kcs, Vcs, A[1]);
  gemm(A[1], Wt[1][3], bia[1][3], A[2], M, 1024, 1024, false, false);      // SH
  gemm(A[3], Wt[2][1], bia[2][1], A[0], M, 1024, 1024, false, false);      // Khp
  gemm(A[3], Wt[2][0], bia[2][0], A[1], M, 1024, 1024, false, false);      // Qhp
  gemm(A[0], Wt[2][2], bia[2][2], A[4], M, 1024, 1024, false, false);      // Vhp
  k_attn<32, 32, false><<<512 * 16, 256, 0, stream>>>(A[1], A[0], A[4], A[3]);
  gemm(A[3], Wt[2][3], bia[2][3], A[1], M, 1024, 1024, false, false);      // PH
  k_ln<0, false><<<M, 256, 0, stream>>>(A[2], A[1], ng[2], nb[2], A[0]);   // DE = LN(SH+PH)
  for (int c = 0; c < M; c += MC) {                                        // mlp2 -> A3
    gemm(A[0] + (size_t)c * 1024, Wm2u, m_b1[1], HbS, MC, 4096, 1024, true, false);
    gemm(HbS, Wm2d, m_b2[1], A[3] + (size_t)c * 1024, MC, 1024, 4096, false, true);
  }
  k_ln<2, true><<<M, 256, 0, stream>>>(A[0], A[3], ng[3], nb[3], d_out);   // final LN+permute, f32
}